// Round 2
// baseline (986.548 us; speedup 1.0000x reference)
//
#include <hip/hip_runtime.h>

// DotProductAttention: H=1024, B=8, S=4096, L=64
// inputs: d_in[0]=hidden f32 [L,B,H], d_in[1]=enc f32 [B,S,2H], d_in[2]=W f32 [H,2H], d_in[3]=bias f32 [H]
// out: context f32 [B,L,H] (524288) then weights f32 [B,S,L] (2097152)
//
// ws layout (needs ~68.4 MiB):
//   reduced fp16 [32768][1024]            67108864 B
//   V       f32  [8][64][2048]             4194304 B
//   partM/partD f32 [8][16][64] each         32768 B each
//   fm/fdinv/sb f32 [8][64] each              2048 B each

#define H_ 1024
#define B_ 8
#define S_ 4096
#define L_ 64
#define K2H 2048
#define M_ 32768

typedef _Float16 f16x8 __attribute__((ext_vector_type(8)));
typedef float f32x4 __attribute__((ext_vector_type(4)));

// ---------------- sb[b][l] = sum_h bias[h]*hidden[l][b][h] ----------------
__global__ __launch_bounds__(256) void ksb_kernel(const float* __restrict__ hidden,
                                                  const float* __restrict__ bias,
                                                  float* __restrict__ sb) {
    const int b = blockIdx.x, t = threadIdx.x;
    const int l = t & 63, j = t >> 6;
    const float* hp = hidden + (size_t)l * (B_ * H_) + b * H_ + j * 256;
    const float* bp = bias + j * 256;
    float s = 0.f;
    for (int i = 0; i < 64; i++) {
        float4 h4 = *(const float4*)(hp + i * 4);
        float4 b4 = *(const float4*)(bp + i * 4);
        s += h4.x * b4.x + h4.y * b4.y + h4.z * b4.z + h4.w * b4.w;
    }
    __shared__ float red[256];
    red[t] = s; __syncthreads();
    if (t < 128) red[t] += red[t + 128];
    __syncthreads();
    if (t < 64) sb[b * 64 + t] = red[t] + red[t + 64];
}

// ---------------- V[b][l][k] = sum_h W[h][k] * hidden[l][b][h]  (fp32 exact) ----------------
__global__ __launch_bounds__(256) void kv_kernel(const float* __restrict__ hidden,
                                                 const float* __restrict__ W,
                                                 float* __restrict__ V) {
    __shared__ float Ah[64][17];   // [l][hh]
    __shared__ float Wt[16][64];   // [hh][k]
    const int b = blockIdx.x;
    const int k0 = blockIdx.y * 64;
    const int t = threadIdx.x;
    const int lt = t & 15, kt = t >> 4;   // l=lt*4+i, k=k0+kt*4+j
    float acc[4][4];
#pragma unroll
    for (int i = 0; i < 4; i++)
#pragma unroll
        for (int j = 0; j < 4; j++) acc[i][j] = 0.f;

    const int ar = t >> 2, ac4 = (t & 3) * 4;      // Ah staging: 64 rows x 4 float4
    const int wrow = t >> 4, wc4 = (t & 15) * 4;   // Wt staging: 16 rows x 16 float4

    for (int h0 = 0; h0 < H_; h0 += 16) {
        float4 av = *(const float4*)(hidden + (size_t)ar * (B_ * H_) + b * H_ + h0 + ac4);
        Ah[ar][ac4 + 0] = av.x; Ah[ar][ac4 + 1] = av.y; Ah[ar][ac4 + 2] = av.z; Ah[ar][ac4 + 3] = av.w;
        *(float4*)&Wt[wrow][wc4] = *(const float4*)(W + (size_t)(h0 + wrow) * K2H + k0 + wc4);
        __syncthreads();
#pragma unroll
        for (int hh = 0; hh < 16; hh++) {
            float a0 = Ah[lt * 4 + 0][hh], a1 = Ah[lt * 4 + 1][hh];
            float a2 = Ah[lt * 4 + 2][hh], a3 = Ah[lt * 4 + 3][hh];
            float4 wv = *(const float4*)&Wt[hh][kt * 4];
            acc[0][0] += a0 * wv.x; acc[0][1] += a0 * wv.y; acc[0][2] += a0 * wv.z; acc[0][3] += a0 * wv.w;
            acc[1][0] += a1 * wv.x; acc[1][1] += a1 * wv.y; acc[1][2] += a1 * wv.z; acc[1][3] += a1 * wv.w;
            acc[2][0] += a2 * wv.x; acc[2][1] += a2 * wv.y; acc[2][2] += a2 * wv.z; acc[2][3] += a2 * wv.w;
            acc[3][0] += a3 * wv.x; acc[3][1] += a3 * wv.y; acc[3][2] += a3 * wv.z; acc[3][3] += a3 * wv.w;
        }
        __syncthreads();
    }
#pragma unroll
    for (int i = 0; i < 4; i++) {
        float4 o; o.x = acc[i][0]; o.y = acc[i][1]; o.z = acc[i][2]; o.w = acc[i][3];
        *(float4*)(V + (size_t)b * (L_ * K2H) + (lt * 4 + i) * K2H + k0 + kt * 4) = o;
    }
}

// ---------------- reduced[m][n] fp16 = sum_k enc[m][k]*W[n][k] + bias[n] ----------------
// 128x128 tile, BK=32, 4 waves 2x2, each wave 64x64 (4x4 MFMA 16x16x32 f16)
__global__ __launch_bounds__(256) void k1_kernel(const float* __restrict__ enc,
                                                 const float* __restrict__ W,
                                                 const float* __restrict__ bias,
                                                 _Float16* __restrict__ reduced) {
    __shared__ _Float16 As[128][40];
    __shared__ _Float16 Bs[128][40];
    const int t = threadIdx.x;
    const int n0 = blockIdx.x * 128;   // x fastest: 8 n-blocks share an A-tile (L2 reuse)
    const int m0 = blockIdx.y * 128;
    const int w = t >> 6, lane = t & 63;
    const int wr = w >> 1, wc = w & 1;
    const int ml = lane & 15, q = lane >> 4;

    f32x4 acc[4][4];
#pragma unroll
    for (int i = 0; i < 4; i++)
#pragma unroll
        for (int j = 0; j < 4; j++) acc[i][j] = (f32x4){0.f, 0.f, 0.f, 0.f};

    const int r0 = t >> 2;           // staging row base (c = t + 256*j -> row = r0 + 64*j)
    const int c8 = (t & 3) * 8;

    for (int k0 = 0; k0 < K2H; k0 += 32) {
#pragma unroll
        for (int j = 0; j < 2; ++j) {
            const int row = r0 + 64 * j;
            const float* pa = enc + (size_t)(m0 + row) * K2H + k0 + c8;
            float4 a0 = *(const float4*)pa, a1 = *(const float4*)(pa + 4);
            f16x8 ha;
            ha[0] = (_Float16)a0.x; ha[1] = (_Float16)a0.y; ha[2] = (_Float16)a0.z; ha[3] = (_Float16)a0.w;
            ha[4] = (_Float16)a1.x; ha[5] = (_Float16)a1.y; ha[6] = (_Float16)a1.z; ha[7] = (_Float16)a1.w;
            *(f16x8*)&As[row][c8] = ha;
            const float* pb = W + (size_t)(n0 + row) * K2H + k0 + c8;
            float4 b0 = *(const float4*)pb, b1 = *(const float4*)(pb + 4);
            f16x8 hb;
            hb[0] = (_Float16)b0.x; hb[1] = (_Float16)b0.y; hb[2] = (_Float16)b0.z; hb[3] = (_Float16)b0.w;
            hb[4] = (_Float16)b1.x; hb[5] = (_Float16)b1.y; hb[6] = (_Float16)b1.z; hb[7] = (_Float16)b1.w;
            *(f16x8*)&Bs[row][c8] = hb;
        }
        __syncthreads();
        f16x8 af[4], bf[4];
#pragma unroll
        for (int i = 0; i < 4; i++) af[i] = *(const f16x8*)&As[wr * 64 + i * 16 + ml][q * 8];
#pragma unroll
        for (int j = 0; j < 4; j++) bf[j] = *(const f16x8*)&Bs[wc * 64 + j * 16 + ml][q * 8];
#pragma unroll
        for (int i = 0; i < 4; i++)
#pragma unroll
            for (int j = 0; j < 4; j++)
                acc[i][j] = __builtin_amdgcn_mfma_f32_16x16x32_f16(af[i], bf[j], acc[i][j], 0, 0, 0);
        __syncthreads();
    }
    // epilogue: C/D layout col=lane&15, row=q*4+r (HW-verified, dtype-independent)
#pragma unroll
    for (int j = 0; j < 4; j++) {
        const int h = n0 + wc * 64 + j * 16 + ml;
        const float bv = bias[h];
#pragma unroll
        for (int i = 0; i < 4; i++) {
            const int srow = m0 + wr * 64 + i * 16 + q * 4;
#pragma unroll
            for (int r = 0; r < 4; r++)
                reduced[(size_t)(srow + r) * H_ + h] = (_Float16)(acc[i][j][r] + bv);
        }
    }
}

// ---------------- scores[b][s][l] = sum_k enc[b][s][k]*V[b][l][k] + sb[b][l]  (split-fp16) ----------------
// 64(s) x 64(l) tile, BK=32, 4 waves each 16x64, 3-product split for ~fp32 accuracy
__global__ __launch_bounds__(256) void ks_kernel(const float* __restrict__ enc,
                                                 const float* __restrict__ V,
                                                 const float* __restrict__ sb,
                                                 float* __restrict__ scores) {
    __shared__ _Float16 AsH[64][40], AsL[64][40];
    __shared__ _Float16 BsH[64][40], BsL[64][40];
    const int t = threadIdx.x;
    const int s0 = blockIdx.x * 64;
    const int b = blockIdx.y;
    const int w = t >> 6, lane = t & 63;
    const int ml = lane & 15, q = lane >> 4;

    f32x4 acc[4];
#pragma unroll
    for (int j = 0; j < 4; j++) acc[j] = (f32x4){0.f, 0.f, 0.f, 0.f};

    const int r0 = t >> 2, c8 = (t & 3) * 8;   // 64 rows x 4 chunks-of-8

    for (int k0 = 0; k0 < K2H; k0 += 32) {
        {   // A tile: enc rows m = b*S + s0+row
            const float* pa = enc + (size_t)(b * S_ + s0 + r0) * K2H + k0 + c8;
            float4 a0 = *(const float4*)pa, a1 = *(const float4*)(pa + 4);
            float xv[8] = {a0.x, a0.y, a0.z, a0.w, a1.x, a1.y, a1.z, a1.w};
            f16x8 hh, ll;
#pragma unroll
            for (int e = 0; e < 8; e++) {
                _Float16 hi = (_Float16)xv[e];
                hh[e] = hi;
                ll[e] = (_Float16)(xv[e] - (float)hi);
            }
            *(f16x8*)&AsH[r0][c8] = hh;
            *(f16x8*)&AsL[r0][c8] = ll;
        }
        {   // B tile: V[b][row][k]
            const float* pb = V + (size_t)b * (L_ * K2H) + (size_t)r0 * K2H + k0 + c8;
            float4 b0 = *(const float4*)pb, b1 = *(const float4*)(pb + 4);
            float xv[8] = {b0.x, b0.y, b0.z, b0.w, b1.x, b1.y, b1.z, b1.w};
            f16x8 hh, ll;
#pragma unroll
            for (int e = 0; e < 8; e++) {
                _Float16 hi = (_Float16)xv[e];
                hh[e] = hi;
                ll[e] = (_Float16)(xv[e] - (float)hi);
            }
            *(f16x8*)&BsH[r0][c8] = hh;
            *(f16x8*)&BsL[r0][c8] = ll;
        }
        __syncthreads();
        f16x8 aH = *(const f16x8*)&AsH[w * 16 + ml][q * 8];
        f16x8 aL = *(const f16x8*)&AsL[w * 16 + ml][q * 8];
#pragma unroll
        for (int j = 0; j < 4; j++) {
            f16x8 bH = *(const f16x8*)&BsH[j * 16 + ml][q * 8];
            f16x8 bL = *(const f16x8*)&BsL[j * 16 + ml][q * 8];
            acc[j] = __builtin_amdgcn_mfma_f32_16x16x32_f16(aH, bH, acc[j], 0, 0, 0);
            acc[j] = __builtin_amdgcn_mfma_f32_16x16x32_f16(aL, bH, acc[j], 0, 0, 0);
            acc[j] = __builtin_amdgcn_mfma_f32_16x16x32_f16(aH, bL, acc[j], 0, 0, 0);
        }
        __syncthreads();
    }
#pragma unroll
    for (int j = 0; j < 4; j++) {
        const int l = j * 16 + ml;
        const float sbv = sb[b * 64 + l];
        const int srow = s0 + w * 16 + q * 4;
#pragma unroll
        for (int r = 0; r < 4; r++)
            scores[(size_t)b * (S_ * L_) + (size_t)(srow + r) * L_ + l] = acc[j][r] + sbv;
    }
}

// ---------------- softmax over s: pass a (chunk partials) ----------------
__global__ __launch_bounds__(256) void k3a_kernel(const float* __restrict__ scores,
                                                  float* __restrict__ partM,
                                                  float* __restrict__ partD) {
    const int b = blockIdx.x, chunk = blockIdx.y;
    const int t = threadIdx.x;
    const int l = t & 63, si = t >> 6;
    const float* p = scores + (size_t)b * (S_ * L_) + (size_t)(chunk * 256 + si * 64) * L_ + l;
    float m = -__builtin_inff(), d = 0.f;
    for (int i = 0; i < 64; i++) {
        float x = p[i * 64];
        if (x > m) { d = d * __expf(m - x) + 1.f; m = x; }
        else d += __expf(x - m);
    }
    __shared__ float sm[256], sd[256];
    sm[t] = m; sd[t] = d; __syncthreads();
    if (t < 128) {
        float m2 = sm[t + 128], d2 = sd[t + 128];
        if (m2 > sm[t]) { sd[t] = sd[t] * __expf(sm[t] - m2) + d2; sm[t] = m2; }
        else sd[t] += d2 * __expf(m2 - sm[t]);
    }
    __syncthreads();
    if (t < 64) {
        float m1 = sm[t], d1 = sd[t], m2 = sm[t + 64], d2 = sd[t + 64];
        if (m2 > m1) { d1 = d1 * __expf(m1 - m2) + d2; m1 = m2; }
        else d1 += d2 * __expf(m2 - m1);
        partM[(b * 16 + chunk) * 64 + t] = m1;
        partD[(b * 16 + chunk) * 64 + t] = d1;
    }
}

// ---------------- softmax pass b: final (m, 1/d) per (b,l) ----------------
__global__ __launch_bounds__(512) void k3b_kernel(const float* __restrict__ partM,
                                                  const float* __restrict__ partD,
                                                  float* __restrict__ fm,
                                                  float* __restrict__ fdinv) {
    const int t = threadIdx.x;   // 512 = 8b x 64l
    const int b = t >> 6, l = t & 63;
    float m = -__builtin_inff(), d = 0.f;
    for (int c = 0; c < 16; c++) {
        float pm = partM[(b * 16 + c) * 64 + l];
        float pd = partD[(b * 16 + c) * 64 + l];
        if (pm > m) { d = d * __expf(m - pm) + pd; m = pm; }
        else d += pd * __expf(pm - m);
    }
    fm[t] = m;
    fdinv[t] = 1.0f / d;
}

// ---------------- softmax pass c: weights = exp(x-m)*inv_d  (in place) ----------------
__global__ __launch_bounds__(256) void k3c_kernel(float* __restrict__ wbuf,
                                                  const float* __restrict__ fm,
                                                  const float* __restrict__ fdinv) {
    const int base = (blockIdx.x * 256 + threadIdx.x) * 8;
    const int b = base >> 18, l0 = base & 63;
    float4 m0 = *(const float4*)(fm + b * 64 + l0);
    float4 m1 = *(const float4*)(fm + b * 64 + l0 + 4);
    float4 i0 = *(const float4*)(fdinv + b * 64 + l0);
    float4 i1 = *(const float4*)(fdinv + b * 64 + l0 + 4);
    float4 x0 = *(const float4*)(wbuf + base);
    float4 x1 = *(const float4*)(wbuf + base + 4);
    float4 y0, y1;
    y0.x = __expf(x0.x - m0.x) * i0.x; y0.y = __expf(x0.y - m0.y) * i0.y;
    y0.z = __expf(x0.z - m0.z) * i0.z; y0.w = __expf(x0.w - m0.w) * i0.w;
    y1.x = __expf(x1.x - m1.x) * i1.x; y1.y = __expf(x1.y - m1.y) * i1.y;
    y1.z = __expf(x1.z - m1.z) * i1.z; y1.w = __expf(x1.w - m1.w) * i1.w;
    *(float4*)(wbuf + base) = y0;
    *(float4*)(wbuf + base + 4) = y1;
}

// ---------------- context[b][l][h] += sum_s weights[b][s][l]*reduced[b*S+s][h] ----------------
// grid (b=8, ht=4, sc=16); each block: 256 s x 256 h, acc[64 l] per thread, fp32 atomics
__global__ __launch_bounds__(256) void k4_kernel(const float* __restrict__ wbuf,
                                                 const _Float16* __restrict__ reduced,
                                                 float* __restrict__ ctx) {
    __shared__ float Ws[64][64];
    __shared__ _Float16 Rs[64][256];
    const int t = threadIdx.x;
    const int b = blockIdx.x, ht = blockIdx.y, sc = blockIdx.z;
    const int h = ht * 256 + t;
    float acc[64];
#pragma unroll
    for (int l = 0; l < 64; l++) acc[l] = 0.f;

    for (int cc = 0; cc < 4; ++cc) {
        const int sbase = sc * 256 + cc * 64;
#pragma unroll
        for (int j = 0; j < 4; j++) {   // Ws: 64x64 f32
            int c = t + 256 * j;
            int row = c >> 4, c4 = (c & 15) * 4;
            *(float4*)&Ws[row][c4] =
                *(const float4*)(wbuf + (size_t)b * (S_ * L_) + (size_t)(sbase + row) * L_ + c4);
        }
#pragma unroll
        for (int j = 0; j < 8; j++) {   // Rs: 64x256 f16
            int c = t + 256 * j;
            int row = c >> 5, ch = (c & 31) * 8;
            *(uint4*)&Rs[row][ch] =
                *(const uint4*)(reduced + (size_t)(b * S_ + sbase + row) * H_ + ht * 256 + ch);
        }
        __syncthreads();
        for (int ss = 0; ss < 64; ++ss) {
            float r = (float)Rs[ss][t];
            const float4* wr = (const float4*)&Ws[ss][0];
#pragma unroll
            for (int u = 0; u < 16; u++) {
                float4 wv = wr[u];
                acc[u * 4 + 0] += wv.x * r;
                acc[u * 4 + 1] += wv.y * r;
                acc[u * 4 + 2] += wv.z * r;
                acc[u * 4 + 3] += wv.w * r;
            }
        }
        __syncthreads();
    }
#pragma unroll
    for (int l = 0; l < 64; l++)
        atomicAdd(ctx + (size_t)((b * 64 + l) << 10) + h, acc[l]);
}

extern "C" void kernel_launch(void* const* d_in, const int* in_sizes, int n_in,
                              void* d_out, int out_size, void* d_ws, size_t ws_size,
                              hipStream_t stream) {
    const float* hidden = (const float*)d_in[0];
    const float* enc    = (const float*)d_in[1];
    const float* W      = (const float*)d_in[2];
    const float* bias   = (const float*)d_in[3];

    float* ctx  = (float*)d_out;                    // [B,L,H] = 524288 f32
    float* wbuf = (float*)d_out + (B_ * L_ * H_);   // [B,S,L] = 2097152 f32 (scores -> weights)

    char* ws = (char*)d_ws;
    _Float16* reduced = (_Float16*)ws;                       // 67108864 B
    float* V     = (float*)(ws + 67108864);                  //  4194304 B
    float* partM = (float*)(ws + 71303168);                  //    32768 B
    float* partD = partM + 8 * 16 * 64;                      //    32768 B
    float* fm    = partD + 8 * 16 * 64;                      //     2048 B
    float* fdinv = fm + 512;                                 //     2048 B
    float* sb    = fdinv + 512;                              //     2048 B

    hipMemsetAsync(ctx, 0, (size_t)B_ * L_ * H_ * sizeof(float), stream);

    ksb_kernel<<<8, 256, 0, stream>>>(hidden, bias, sb);
    kv_kernel<<<dim3(8, 32), 256, 0, stream>>>(hidden, W, V);
    k1_kernel<<<dim3(8, 256), 256, 0, stream>>>(enc, W, bias, reduced);
    ks_kernel<<<dim3(64, 8), 256, 0, stream>>>(enc, V, sb, wbuf);
    k3a_kernel<<<dim3(8, 16), 256, 0, stream>>>(wbuf, partM, partD);
    k3b_kernel<<<1, 512, 0, stream>>>(partM, partD, fm, fdinv);
    k3c_kernel<<<2097152 / (256 * 8), 256, 0, stream>>>(wbuf, fm, fdinv);
    k4_kernel<<<dim3(8, 4, 16), 256, 0, stream>>>(wbuf, reduced, ctx);
}

// Round 3
// 922.942 us; speedup vs baseline: 1.0689x; 1.0689x over previous
//
#include <hip/hip_runtime.h>

// DotProductAttention: H=1024, B=8, S=4096, L=64
// inputs: d_in[0]=hidden f32 [L,B,H], d_in[1]=enc f32 [B,S,2H], d_in[2]=W f32 [H,2H], d_in[3]=bias f32 [H]
// out: context f32 [B,L,H] (524288) then weights f32 [B,S,L] (2097152)
//
// FAST path (ws_size >= 344004608): enc/W pre-cast to fp16 in MFMA-fragment-tiled
// layout, k1/ks use global_load_lds (16B) staging, conflict-free ds_read_b128.
// FALLBACK path (smaller ws): round-2 kernels verbatim (known-pass, 986 us).

#define H_ 1024
#define B_ 8
#define S_ 4096
#define L_ 64
#define K2H 2048
#define M_ 32768

typedef _Float16 f16x8 __attribute__((ext_vector_type(8)));
typedef float f32x4 __attribute__((ext_vector_type(4)));

typedef const __attribute__((address_space(1))) void* gas_ptr_t;
typedef __attribute__((address_space(3))) void* las_ptr_t;

__device__ __forceinline__ void gload16(const _Float16* g, _Float16* l) {
    __builtin_amdgcn_global_load_lds((gas_ptr_t)g, (las_ptr_t)l, 16, 0, 0);
}

// Fragment-tiled fp16 layout (A/B operand of mfma 16x16x32 f16):
//   tile = (row/16, k/32); within tile: lane = ((k%32)/8)*16 + row%16, elem = k%8
//   linear elem index = (tile_row*(K/32) + tile_k)*512 + lane*8 + elem

// ---------------- cast fp32 [rows][2048] -> fragment-tiled fp16 hi (+ optional lo) ----------------
// grid: (rows/16, 4); block 256. Fully coalesced reads and writes; LDS transpose.
__global__ __launch_bounds__(256) void kcast_kernel(const float* __restrict__ src,
                                                    _Float16* __restrict__ hi,
                                                    _Float16* __restrict__ lo) {
    __shared__ float T[16][516];
    const int t = threadIdx.x;
    const int slab = blockIdx.x, ksec = blockIdx.y;
    const float* sp = src + (size_t)slab * 16 * K2H + ksec * 512;
#pragma unroll
    for (int r = 0; r < 8; r++) {
        int lin = r * 1024 + t * 4;
        int row = lin >> 9, col = lin & 511;
        float4 v = *(const float4*)(sp + (size_t)row * K2H + col);
        T[row][col] = v.x; T[row][col + 1] = v.y; T[row][col + 2] = v.z; T[row][col + 3] = v.w;
    }
    __syncthreads();
    const size_t obase = ((size_t)slab * 64 + ksec * 16) * 512;
#pragma unroll
    for (int r = 0; r < 4; r++) {
        int c = r * 256 + t;
        int kt = c >> 6, lam = c & 63;
        int m = lam & 15, kb = kt * 32 + (lam >> 4) * 8;
        f16x8 h, l;
#pragma unroll
        for (int e = 0; e < 8; e++) {
            float x = T[m][kb + e];
            _Float16 hh = (_Float16)x;
            h[e] = hh;
            l[e] = (_Float16)(x - (float)hh);
        }
        *(f16x8*)(hi + obase + (size_t)c * 8) = h;
        if (lo) *(f16x8*)(lo + obase + (size_t)c * 8) = l;
    }
}

// ---------------- sb[b][l] = sum_h bias[h]*hidden[l][b][h] ----------------
__global__ __launch_bounds__(256) void ksb_kernel(const float* __restrict__ hidden,
                                                  const float* __restrict__ bias,
                                                  float* __restrict__ sb) {
    const int b = blockIdx.x, t = threadIdx.x;
    const int l = t & 63, j = t >> 6;
    const float* hp = hidden + (size_t)l * (B_ * H_) + b * H_ + j * 256;
    const float* bp = bias + j * 256;
    float s = 0.f;
    for (int i = 0; i < 64; i++) {
        float4 h4 = *(const float4*)(hp + i * 4);
        float4 b4 = *(const float4*)(bp + i * 4);
        s += h4.x * b4.x + h4.y * b4.y + h4.z * b4.z + h4.w * b4.w;
    }
    __shared__ float red[256];
    red[t] = s; __syncthreads();
    if (t < 128) red[t] += red[t + 128];
    __syncthreads();
    if (t < 64) sb[b * 64 + t] = red[t] + red[t + 64];
}

// ---------------- kv2: V[b][l][k] = sum_h W[h][k]*hidden[l][b][h] (fp32) -> tiled fp16 hi/lo ----------------
__global__ __launch_bounds__(256) void kv2_kernel(const float* __restrict__ hidden,
                                                  const float* __restrict__ W,
                                                  _Float16* __restrict__ vh,
                                                  _Float16* __restrict__ vl) {
    __shared__ float Ah[64][17];
    __shared__ float Wt[16][64];
    const int b = blockIdx.x;
    const int k0 = blockIdx.y * 64;
    const int t = threadIdx.x;
    const int lt = t & 15, kt = t >> 4;
    float acc[4][4];
#pragma unroll
    for (int i = 0; i < 4; i++)
#pragma unroll
        for (int j = 0; j < 4; j++) acc[i][j] = 0.f;

    const int ar = t >> 2, ac4 = (t & 3) * 4;
    const int wrow = t >> 4, wc4 = (t & 15) * 4;

    for (int h0 = 0; h0 < H_; h0 += 16) {
        float4 av = *(const float4*)(hidden + (size_t)ar * (B_ * H_) + b * H_ + h0 + ac4);
        Ah[ar][ac4 + 0] = av.x; Ah[ar][ac4 + 1] = av.y; Ah[ar][ac4 + 2] = av.z; Ah[ar][ac4 + 3] = av.w;
        *(float4*)&Wt[wrow][wc4] = *(const float4*)(W + (size_t)(h0 + wrow) * K2H + k0 + wc4);
        __syncthreads();
#pragma unroll
        for (int hh = 0; hh < 16; hh++) {
            float a0 = Ah[lt * 4 + 0][hh], a1 = Ah[lt * 4 + 1][hh];
            float a2 = Ah[lt * 4 + 2][hh], a3 = Ah[lt * 4 + 3][hh];
            float4 wv = *(const float4*)&Wt[hh][kt * 4];
            acc[0][0] += a0 * wv.x; acc[0][1] += a0 * wv.y; acc[0][2] += a0 * wv.z; acc[0][3] += a0 * wv.w;
            acc[1][0] += a1 * wv.x; acc[1][1] += a1 * wv.y; acc[1][2] += a1 * wv.z; acc[1][3] += a1 * wv.w;
            acc[2][0] += a2 * wv.x; acc[2][1] += a2 * wv.y; acc[2][2] += a2 * wv.z; acc[2][3] += a2 * wv.w;
            acc[3][0] += a3 * wv.x; acc[3][1] += a3 * wv.y; acc[3][2] += a3 * wv.z; acc[3][3] += a3 * wv.w;
        }
        __syncthreads();
    }
#pragma unroll
    for (int i = 0; i < 4; i++) {
        const int l = lt * 4 + i;
        const int ltile = l >> 4, lam = l & 15;
#pragma unroll
        for (int j = 0; j < 4; j++) {
            const int k = k0 + kt * 4 + j;
            const size_t idx = (((size_t)(b * 4 + ltile) * 64) + (k >> 5)) * 512
                             + (size_t)((((k >> 3) & 3) * 16 + lam) * 8 + (k & 7));
            float v = acc[i][j];
            _Float16 hh = (_Float16)v;
            vh[idx] = hh;
            vl[idx] = (_Float16)(v - (float)hh);
        }
    }
}

// ---------------- k1f: reduced[m][n] fp16 = enc16 @ W16^T + bias, global_load_lds staging ----------------
__global__ __launch_bounds__(256) void k1f_kernel(const _Float16* __restrict__ eh,
                                                  const _Float16* __restrict__ wh,
                                                  const float* __restrict__ bias,
                                                  _Float16* __restrict__ reduced) {
    __shared__ _Float16 As[8192];   // [mtile 8][kk 2][512] fragment chunks
    __shared__ _Float16 Bs[8192];
    const int t = threadIdx.x;
    const int n0 = blockIdx.x * 128, m0 = blockIdx.y * 128;
    const int w = t >> 6, lane = t & 63;
    const int wr = w >> 1, wc = w & 1;
    const int ml = lane & 15, q = lane >> 4;

    f32x4 acc[4][4] = {};
    const bool isA = (w < 2);
    const int cbase = (w & 1) * 8;
    const _Float16* gsrc = isA ? eh : wh;
    const int rtile0 = isA ? (m0 >> 4) : (n0 >> 4);
    _Float16* lds = isA ? As : Bs;

    for (int kt0 = 0; kt0 < 64; kt0 += 2) {
#pragma unroll
        for (int li = 0; li < 8; li++) {
            const int c = cbase + li;
            const size_t goff = ((size_t)(rtile0 + (c >> 1)) * 64 + kt0 + (c & 1)) * 512 + lane * 8;
            gload16(gsrc + goff, lds + c * 512);
        }
        __syncthreads();
#pragma unroll
        for (int kk = 0; kk < 2; kk++) {
            f16x8 af[4], bf[4];
#pragma unroll
            for (int i = 0; i < 4; i++) af[i] = *(const f16x8*)&As[(size_t)(((wr * 4 + i) * 2 + kk) * 512 + lane * 8)];
#pragma unroll
            for (int j = 0; j < 4; j++) bf[j] = *(const f16x8*)&Bs[(size_t)(((wc * 4 + j) * 2 + kk) * 512 + lane * 8)];
#pragma unroll
            for (int i = 0; i < 4; i++)
#pragma unroll
                for (int j = 0; j < 4; j++)
                    acc[i][j] = __builtin_amdgcn_mfma_f32_16x16x32_f16(af[i], bf[j], acc[i][j], 0, 0, 0);
        }
        __syncthreads();
    }
#pragma unroll
    for (int j = 0; j < 4; j++) {
        const int h = n0 + wc * 64 + j * 16 + ml;
        const float bv = bias[h];
#pragma unroll
        for (int i = 0; i < 4; i++) {
            const int srow = m0 + wr * 64 + i * 16 + q * 4;
#pragma unroll
            for (int r = 0; r < 4; r++)
                reduced[(size_t)(srow + r) * H_ + h] = (_Float16)(acc[i][j][r] + bv);
        }
    }
}

// ---------------- ksf: scores = enc(hi+lo) @ V(hi+lo)^T + sb, split-fp16, global_load_lds ----------------
__global__ __launch_bounds__(256) void ksf_kernel(const _Float16* __restrict__ eh,
                                                  const _Float16* __restrict__ el,
                                                  const _Float16* __restrict__ vh,
                                                  const _Float16* __restrict__ vl,
                                                  const float* __restrict__ sb,
                                                  float* __restrict__ scores) {
    __shared__ _Float16 AH[4096], AL[4096], BH[4096], BL[4096];  // [tile 4][kk 2][512]
    const int t = threadIdx.x;
    const int s0 = blockIdx.x * 64;
    const int b = blockIdx.y;
    const int w = t >> 6, lane = t & 63;
    const int ml = lane & 15, q = lane >> 4;
    f32x4 acc[4] = {};
    const int mt0 = (b * S_ + s0) >> 4;
    const int lt0 = b * 4;
    const _Float16* gsrc = (w == 0) ? eh : (w == 1) ? el : (w == 2) ? vh : vl;
    _Float16* lds = (w == 0) ? AH : (w == 1) ? AL : (w == 2) ? BH : BL;
    const int rt0 = (w < 2) ? mt0 : lt0;

    for (int kt0 = 0; kt0 < 64; kt0 += 2) {
#pragma unroll
        for (int li = 0; li < 8; li++) {
            const size_t goff = ((size_t)(rt0 + (li >> 1)) * 64 + kt0 + (li & 1)) * 512 + lane * 8;
            gload16(gsrc + goff, lds + li * 512);
        }
        __syncthreads();
#pragma unroll
        for (int kk = 0; kk < 2; kk++) {
            f16x8 aH = *(const f16x8*)&AH[(size_t)((w * 2 + kk) * 512 + lane * 8)];
            f16x8 aL = *(const f16x8*)&AL[(size_t)((w * 2 + kk) * 512 + lane * 8)];
#pragma unroll
            for (int j = 0; j < 4; j++) {
                f16x8 bH = *(const f16x8*)&BH[(size_t)((j * 2 + kk) * 512 + lane * 8)];
                f16x8 bL = *(const f16x8*)&BL[(size_t)((j * 2 + kk) * 512 + lane * 8)];
                acc[j] = __builtin_amdgcn_mfma_f32_16x16x32_f16(aH, bH, acc[j], 0, 0, 0);
                acc[j] = __builtin_amdgcn_mfma_f32_16x16x32_f16(aL, bH, acc[j], 0, 0, 0);
                acc[j] = __builtin_amdgcn_mfma_f32_16x16x32_f16(aH, bL, acc[j], 0, 0, 0);
            }
        }
        __syncthreads();
    }
#pragma unroll
    for (int j = 0; j < 4; j++) {
        const int l = j * 16 + ml;
        const float sbv = sb[b * 64 + l];
        const int srow = s0 + w * 16 + q * 4;
#pragma unroll
        for (int r = 0; r < 4; r++)
            scores[(size_t)b * (S_ * L_) + (size_t)(srow + r) * L_ + l] = acc[j][r] + sbv;
    }
}

// ================= fallback (round-2) kernels =================

__global__ __launch_bounds__(256) void kv_kernel(const float* __restrict__ hidden,
                                                 const float* __restrict__ W,
                                                 float* __restrict__ V) {
    __shared__ float Ah[64][17];
    __shared__ float Wt[16][64];
    const int b = blockIdx.x;
    const int k0 = blockIdx.y * 64;
    const int t = threadIdx.x;
    const int lt = t & 15, kt = t >> 4;
    float acc[4][4];
#pragma unroll
    for (int i = 0; i < 4; i++)
#pragma unroll
        for (int j = 0; j < 4; j++) acc[i][j] = 0.f;

    const int ar = t >> 2, ac4 = (t & 3) * 4;
    const int wrow = t >> 4, wc4 = (t & 15) * 4;

    for (int h0 = 0; h0 < H_; h0 += 16) {
        float4 av = *(const float4*)(hidden + (size_t)ar * (B_ * H_) + b * H_ + h0 + ac4);
        Ah[ar][ac4 + 0] = av.x; Ah[ar][ac4 + 1] = av.y; Ah[ar][ac4 + 2] = av.z; Ah[ar][ac4 + 3] = av.w;
        *(float4*)&Wt[wrow][wc4] = *(const float4*)(W + (size_t)(h0 + wrow) * K2H + k0 + wc4);
        __syncthreads();
#pragma unroll
        for (int hh = 0; hh < 16; hh++) {
            float a0 = Ah[lt * 4 + 0][hh], a1 = Ah[lt * 4 + 1][hh];
            float a2 = Ah[lt * 4 + 2][hh], a3 = Ah[lt * 4 + 3][hh];
            float4 wv = *(const float4*)&Wt[hh][kt * 4];
            acc[0][0] += a0 * wv.x; acc[0][1] += a0 * wv.y; acc[0][2] += a0 * wv.z; acc[0][3] += a0 * wv.w;
            acc[1][0] += a1 * wv.x; acc[1][1] += a1 * wv.y; acc[1][2] += a1 * wv.z; acc[1][3] += a1 * wv.w;
            acc[2][0] += a2 * wv.x; acc[2][1] += a2 * wv.y; acc[2][2] += a2 * wv.z; acc[2][3] += a2 * wv.w;
            acc[3][0] += a3 * wv.x; acc[3][1] += a3 * wv.y; acc[3][2] += a3 * wv.z; acc[3][3] += a3 * wv.w;
        }
        __syncthreads();
    }
#pragma unroll
    for (int i = 0; i < 4; i++) {
        float4 o; o.x = acc[i][0]; o.y = acc[i][1]; o.z = acc[i][2]; o.w = acc[i][3];
        *(float4*)(V + (size_t)b * (L_ * K2H) + (lt * 4 + i) * K2H + k0 + kt * 4) = o;
    }
}

__global__ __launch_bounds__(256) void k1_kernel(const float* __restrict__ enc,
                                                 const float* __restrict__ W,
                                                 const float* __restrict__ bias,
                                                 _Float16* __restrict__ reduced) {
    __shared__ _Float16 As[128][40];
    __shared__ _Float16 Bs[128][40];
    const int t = threadIdx.x;
    const int n0 = blockIdx.x * 128;
    const int m0 = blockIdx.y * 128;
    const int w = t >> 6, lane = t & 63;
    const int wr = w >> 1, wc = w & 1;
    const int ml = lane & 15, q = lane >> 4;

    f32x4 acc[4][4];
#pragma unroll
    for (int i = 0; i < 4; i++)
#pragma unroll
        for (int j = 0; j < 4; j++) acc[i][j] = (f32x4){0.f, 0.f, 0.f, 0.f};

    const int r0 = t >> 2;
    const int c8 = (t & 3) * 8;

    for (int k0 = 0; k0 < K2H; k0 += 32) {
#pragma unroll
        for (int j = 0; j < 2; ++j) {
            const int row = r0 + 64 * j;
            const float* pa = enc + (size_t)(m0 + row) * K2H + k0 + c8;
            float4 a0 = *(const float4*)pa, a1 = *(const float4*)(pa + 4);
            f16x8 ha;
            ha[0] = (_Float16)a0.x; ha[1] = (_Float16)a0.y; ha[2] = (_Float16)a0.z; ha[3] = (_Float16)a0.w;
            ha[4] = (_Float16)a1.x; ha[5] = (_Float16)a1.y; ha[6] = (_Float16)a1.z; ha[7] = (_Float16)a1.w;
            *(f16x8*)&As[row][c8] = ha;
            const float* pb = W + (size_t)(n0 + row) * K2H + k0 + c8;
            float4 b0 = *(const float4*)pb, b1 = *(const float4*)(pb + 4);
            f16x8 hb;
            hb[0] = (_Float16)b0.x; hb[1] = (_Float16)b0.y; hb[2] = (_Float16)b0.z; hb[3] = (_Float16)b0.w;
            hb[4] = (_Float16)b1.x; hb[5] = (_Float16)b1.y; hb[6] = (_Float16)b1.z; hb[7] = (_Float16)b1.w;
            *(f16x8*)&Bs[row][c8] = hb;
        }
        __syncthreads();
        f16x8 af[4], bf[4];
#pragma unroll
        for (int i = 0; i < 4; i++) af[i] = *(const f16x8*)&As[wr * 64 + i * 16 + ml][q * 8];
#pragma unroll
        for (int j = 0; j < 4; j++) bf[j] = *(const f16x8*)&Bs[wc * 64 + j * 16 + ml][q * 8];
#pragma unroll
        for (int i = 0; i < 4; i++)
#pragma unroll
            for (int j = 0; j < 4; j++)
                acc[i][j] = __builtin_amdgcn_mfma_f32_16x16x32_f16(af[i], bf[j], acc[i][j], 0, 0, 0);
        __syncthreads();
    }
#pragma unroll
    for (int j = 0; j < 4; j++) {
        const int h = n0 + wc * 64 + j * 16 + ml;
        const float bv = bias[h];
#pragma unroll
        for (int i = 0; i < 4; i++) {
            const int srow = m0 + wr * 64 + i * 16 + q * 4;
#pragma unroll
            for (int r = 0; r < 4; r++)
                reduced[(size_t)(srow + r) * H_ + h] = (_Float16)(acc[i][j][r] + bv);
        }
    }
}

__global__ __launch_bounds__(256) void ks_kernel(const float* __restrict__ enc,
                                                 const float* __restrict__ V,
                                                 const float* __restrict__ sb,
                                                 float* __restrict__ scores) {
    __shared__ _Float16 AsH[64][40], AsL[64][40];
    __shared__ _Float16 BsH[64][40], BsL[64][40];
    const int t = threadIdx.x;
    const int s0 = blockIdx.x * 64;
    const int b = blockIdx.y;
    const int w = t >> 6, lane = t & 63;
    const int ml = lane & 15, q = lane >> 4;

    f32x4 acc[4];
#pragma unroll
    for (int j = 0; j < 4; j++) acc[j] = (f32x4){0.f, 0.f, 0.f, 0.f};

    const int r0 = t >> 2, c8 = (t & 3) * 8;

    for (int k0 = 0; k0 < K2H; k0 += 32) {
        {
            const float* pa = enc + (size_t)(b * S_ + s0 + r0) * K2H + k0 + c8;
            float4 a0 = *(const float4*)pa, a1 = *(const float4*)(pa + 4);
            float xv[8] = {a0.x, a0.y, a0.z, a0.w, a1.x, a1.y, a1.z, a1.w};
            f16x8 hh, ll;
#pragma unroll
            for (int e = 0; e < 8; e++) {
                _Float16 hi = (_Float16)xv[e];
                hh[e] = hi;
                ll[e] = (_Float16)(xv[e] - (float)hi);
            }
            *(f16x8*)&AsH[r0][c8] = hh;
            *(f16x8*)&AsL[r0][c8] = ll;
        }
        {
            const float* pb = V + (size_t)b * (L_ * K2H) + (size_t)r0 * K2H + k0 + c8;
            float4 b0 = *(const float4*)pb, b1 = *(const float4*)(pb + 4);
            float xv[8] = {b0.x, b0.y, b0.z, b0.w, b1.x, b1.y, b1.z, b1.w};
            f16x8 hh, ll;
#pragma unroll
            for (int e = 0; e < 8; e++) {
                _Float16 hi = (_Float16)xv[e];
                hh[e] = hi;
                ll[e] = (_Float16)(xv[e] - (float)hi);
            }
            *(f16x8*)&BsH[r0][c8] = hh;
            *(f16x8*)&BsL[r0][c8] = ll;
        }
        __syncthreads();
        f16x8 aH = *(const f16x8*)&AsH[w * 16 + ml][q * 8];
        f16x8 aL = *(const f16x8*)&AsL[w * 16 + ml][q * 8];
#pragma unroll
        for (int j = 0; j < 4; j++) {
            f16x8 bH = *(const f16x8*)&BsH[j * 16 + ml][q * 8];
            f16x8 bL = *(const f16x8*)&BsL[j * 16 + ml][q * 8];
            acc[j] = __builtin_amdgcn_mfma_f32_16x16x32_f16(aH, bH, acc[j], 0, 0, 0);
            acc[j] = __builtin_amdgcn_mfma_f32_16x16x32_f16(aL, bH, acc[j], 0, 0, 0);
            acc[j] = __builtin_amdgcn_mfma_f32_16x16x32_f16(aH, bL, acc[j], 0, 0, 0);
        }
        __syncthreads();
    }
#pragma unroll
    for (int j = 0; j < 4; j++) {
        const int l = j * 16 + ml;
        const float sbv = sb[b * 64 + l];
        const int srow = s0 + w * 16 + q * 4;
#pragma unroll
        for (int r = 0; r < 4; r++)
            scores[(size_t)b * (S_ * L_) + (size_t)(srow + r) * L_ + l] = acc[j][r] + sbv;
    }
}

// ================= shared (both paths) =================

__global__ __launch_bounds__(256) void k3a_kernel(const float* __restrict__ scores,
                                                  float* __restrict__ partM,
                                                  float* __restrict__ partD) {
    const int b = blockIdx.x, chunk = blockIdx.y;
    const int t = threadIdx.x;
    const int l = t & 63, si = t >> 6;
    const float* p = scores + (size_t)b * (S_ * L_) + (size_t)(chunk * 256 + si * 64) * L_ + l;
    float m = -__builtin_inff(), d = 0.f;
    for (int i = 0; i < 64; i++) {
        float x = p[i * 64];
        if (x > m) { d = d * __expf(m - x) + 1.f; m = x; }
        else d += __expf(x - m);
    }
    __shared__ float sm[256], sd[256];
    sm[t] = m; sd[t] = d; __syncthreads();
    if (t < 128) {
        float m2 = sm[t + 128], d2 = sd[t + 128];
        if (m2 > sm[t]) { sd[t] = sd[t] * __expf(sm[t] - m2) + d2; sm[t] = m2; }
        else sd[t] += d2 * __expf(m2 - sm[t]);
    }
    __syncthreads();
    if (t < 64) {
        float m1 = sm[t], d1 = sd[t], m2 = sm[t + 64], d2 = sd[t + 64];
        if (m2 > m1) { d1 = d1 * __expf(m1 - m2) + d2; m1 = m2; }
        else d1 += d2 * __expf(m2 - m1);
        partM[(b * 16 + chunk) * 64 + t] = m1;
        partD[(b * 16 + chunk) * 64 + t] = d1;
    }
}

__global__ __launch_bounds__(512) void k3b_kernel(const float* __restrict__ partM,
                                                  const float* __restrict__ partD,
                                                  float* __restrict__ fm,
                                                  float* __restrict__ fdinv) {
    const int t = threadIdx.x;
    const int b = t >> 6, l = t & 63;
    float m = -__builtin_inff(), d = 0.f;
    for (int c = 0; c < 16; c++) {
        float pm = partM[(b * 16 + c) * 64 + l];
        float pd = partD[(b * 16 + c) * 64 + l];
        if (pm > m) { d = d * __expf(m - pm) + pd; m = pm; }
        else d += pd * __expf(pm - m);
    }
    fm[t] = m;
    fdinv[t] = 1.0f / d;
}

__global__ __launch_bounds__(256) void k3c_kernel(float* __restrict__ wbuf,
                                                  const float* __restrict__ fm,
                                                  const float* __restrict__ fdinv) {
    const int base = (blockIdx.x * 256 + threadIdx.x) * 8;
    const int b = base >> 18, l0 = base & 63;
    float4 m0 = *(const float4*)(fm + b * 64 + l0);
    float4 m1 = *(const float4*)(fm + b * 64 + l0 + 4);
    float4 i0 = *(const float4*)(fdinv + b * 64 + l0);
    float4 i1 = *(const float4*)(fdinv + b * 64 + l0 + 4);
    float4 x0 = *(const float4*)(wbuf + base);
    float4 x1 = *(const float4*)(wbuf + base + 4);
    float4 y0, y1;
    y0.x = __expf(x0.x - m0.x) * i0.x; y0.y = __expf(x0.y - m0.y) * i0.y;
    y0.z = __expf(x0.z - m0.z) * i0.z; y0.w = __expf(x0.w - m0.w) * i0.w;
    y1.x = __expf(x1.x - m1.x) * i1.x; y1.y = __expf(x1.y - m1.y) * i1.y;
    y1.z = __expf(x1.z - m1.z) * i1.z; y1.w = __expf(x1.w - m1.w) * i1.w;
    *(float4*)(wbuf + base) = y0;
    *(float4*)(wbuf + base + 4) = y1;
}

__global__ __launch_bounds__(256) void k4_kernel(const float* __restrict__ wbuf,
                                                 const _Float16* __restrict__ reduced,
                                                 float* __restrict__ ctx) {
    __shared__ float Ws[64][64];
    __shared__ _Float16 Rs[64][256];
    const int t = threadIdx.x;
    const int b = blockIdx.x, ht = blockIdx.y, sc = blockIdx.z;
    const int h = ht * 256 + t;
    float acc[64];
#pragma unroll
    for (int l = 0; l < 64; l++) acc[l] = 0.f;

    for (int cc = 0; cc < 4; ++cc) {
        const int sbase = sc * 256 + cc * 64;
#pragma unroll
        for (int j = 0; j < 4; j++) {
            int c = t + 256 * j;
            int row = c >> 4, c4 = (c & 15) * 4;
            *(float4*)&Ws[row][c4] =
                *(const float4*)(wbuf + (size_t)b * (S_ * L_) + (size_t)(sbase + row) * L_ + c4);
        }
#pragma unroll
        for (int j = 0; j < 8; j++) {
            int c = t + 256 * j;
            int row = c >> 5, ch = (c & 31) * 8;
            *(uint4*)&Rs[row][ch] =
                *(const uint4*)(reduced + (size_t)(b * S_ + sbase + row) * H_ + ht * 256 + ch);
        }
        __syncthreads();
        for (int ss = 0; ss < 64; ++ss) {
            float r = (float)Rs[ss][t];
            const float4* wr = (const float4*)&Ws[ss][0];
#pragma unroll
            for (int u = 0; u < 16; u++) {
                float4 wv = wr[u];
                acc[u * 4 + 0] += wv.x * r;
                acc[u * 4 + 1] += wv.y * r;
                acc[u * 4 + 2] += wv.z * r;
                acc[u * 4 + 3] += wv.w * r;
            }
        }
        __syncthreads();
    }
#pragma unroll
    for (int l = 0; l < 64; l++)
        atomicAdd(ctx + (size_t)((b * 64 + l) << 10) + h, acc[l]);
}

extern "C" void kernel_launch(void* const* d_in, const int* in_sizes, int n_in,
                              void* d_out, int out_size, void* d_ws, size_t ws_size,
                              hipStream_t stream) {
    const float* hidden = (const float*)d_in[0];
    const float* enc    = (const float*)d_in[1];
    const float* W      = (const float*)d_in[2];
    const float* bias   = (const float*)d_in[3];

    float* ctx  = (float*)d_out;
    float* wbuf = (float*)d_out + (B_ * L_ * H_);

    char* ws = (char*)d_ws;
    const size_t NEED_FAST = 344004608;

    hipMemsetAsync(ctx, 0, (size_t)B_ * L_ * H_ * sizeof(float), stream);

    if (ws_size >= NEED_FAST) {
        _Float16* enc_hi  = (_Float16*)ws;                          // 134217728 B
        _Float16* enc_lo  = (_Float16*)(ws + 134217728);            // 134217728 B
        _Float16* reduced = (_Float16*)(ws + 268435456);            //  67108864 B
        _Float16* w16     = (_Float16*)(ws + 335544320);            //   4194304 B
        _Float16* vh      = (_Float16*)(ws + 339738624);            //   2097152 B
        _Float16* vl      = (_Float16*)(ws + 341835776);            //   2097152 B
        float* partM = (float*)(ws + 343932928);
        float* partD = partM + 8 * 16 * 64;
        float* fm    = partD + 8 * 16 * 64;
        float* fdinv = fm + 512;
        float* sb    = fdinv + 512;

        kcast_kernel<<<dim3(2048, 4), 256, 0, stream>>>(enc, enc_hi, enc_lo);
        kcast_kernel<<<dim3(64, 4), 256, 0, stream>>>(W, w16, (_Float16*)nullptr);
        ksb_kernel<<<8, 256, 0, stream>>>(hidden, bias, sb);
        kv2_kernel<<<dim3(8, 32), 256, 0, stream>>>(hidden, W, vh, vl);
        k1f_kernel<<<dim3(8, 256), 256, 0, stream>>>(enc_hi, w16, bias, reduced);
        ksf_kernel<<<dim3(64, 8), 256, 0, stream>>>(enc_hi, enc_lo, vh, vl, sb, wbuf);
        k3a_kernel<<<dim3(8, 16), 256, 0, stream>>>(wbuf, partM, partD);
        k3b_kernel<<<1, 512, 0, stream>>>(partM, partD, fm, fdinv);
        k3c_kernel<<<2097152 / (256 * 8), 256, 0, stream>>>(wbuf, fm, fdinv);
        k4_kernel<<<dim3(8, 4, 16), 256, 0, stream>>>(wbuf, reduced, ctx);
    } else {
        _Float16* reduced = (_Float16*)ws;                       // 67108864 B
        float* V     = (float*)(ws + 67108864);                  //  4194304 B
        float* partM = (float*)(ws + 71303168);
        float* partD = partM + 8 * 16 * 64;
        float* fm    = partD + 8 * 16 * 64;
        float* fdinv = fm + 512;
        float* sb    = fdinv + 512;

        ksb_kernel<<<8, 256, 0, stream>>>(hidden, bias, sb);
        kv_kernel<<<dim3(8, 32), 256, 0, stream>>>(hidden, W, V);
        k1_kernel<<<dim3(8, 256), 256, 0, stream>>>(enc, W, bias, reduced);
        ks_kernel<<<dim3(64, 8), 256, 0, stream>>>(enc, V, sb, wbuf);
        k3a_kernel<<<dim3(8, 16), 256, 0, stream>>>(wbuf, partM, partD);
        k3b_kernel<<<1, 512, 0, stream>>>(partM, partD, fm, fdinv);
        k3c_kernel<<<2097152 / (256 * 8), 256, 0, stream>>>(wbuf, fm, fdinv);
        k4_kernel<<<dim3(8, 4, 16), 256, 0, stream>>>(wbuf, reduced, ctx);
    }
}

// Round 4
// 790.498 us; speedup vs baseline: 1.2480x; 1.1675x over previous
//
#include <hip/hip_runtime.h>

// DotProductAttention: H=1024, B=8, S=4096, L=64
// inputs: d_in[0]=hidden f32 [L,B,H], d_in[1]=enc f32 [B,S,2H], d_in[2]=W f32 [H,2H], d_in[3]=bias f32 [H]
// out: context f32 [B,L,H] (524288) then weights f32 [B,S,L] (2097152)
//
// FAST path (ws_size >= 344004608): all GEMMs MFMA with fragment-tiled fp16
// operands + global_load_lds staging. k4 is now MFMA (k4f) fed by
// B-fragment reduced (k1f epilogue) and A-fragment fp16 weights (k3c epilogue).
// FALLBACK path: round-2 kernels verbatim (known-pass, 986 us).

#define H_ 1024
#define B_ 8
#define S_ 4096
#define L_ 64
#define K2H 2048
#define M_ 32768

typedef _Float16 f16x8 __attribute__((ext_vector_type(8)));
typedef _Float16 f16x4 __attribute__((ext_vector_type(4)));
typedef float f32x4 __attribute__((ext_vector_type(4)));

typedef const __attribute__((address_space(1))) void* gas_ptr_t;
typedef __attribute__((address_space(3))) void* las_ptr_t;

__device__ __forceinline__ void gload16(const _Float16* g, _Float16* l) {
    __builtin_amdgcn_global_load_lds((gas_ptr_t)g, (las_ptr_t)l, 16, 0, 0);
}

// Fragment layout (A/B operand of mfma 16x16x32 f16), rows=m-or-n, k:
//   tile = (row/16, k/32); lane = ((k%32)/8)*16 + row%16, elem = k%8
//   linear = (tile_row*NTK + tile_k)*512 + lane*8 + elem

// ---------------- cast fp32 [rows][2048] -> fragment-tiled fp16 hi (+ optional lo) ----------------
__global__ __launch_bounds__(256) void kcast_kernel(const float* __restrict__ src,
                                                    _Float16* __restrict__ hi,
                                                    _Float16* __restrict__ lo) {
    __shared__ float T[16][516];
    const int t = threadIdx.x;
    const int slab = blockIdx.x, ksec = blockIdx.y;
    const float* sp = src + (size_t)slab * 16 * K2H + ksec * 512;
#pragma unroll
    for (int r = 0; r < 8; r++) {
        int lin = r * 1024 + t * 4;
        int row = lin >> 9, col = lin & 511;
        float4 v = *(const float4*)(sp + (size_t)row * K2H + col);
        T[row][col] = v.x; T[row][col + 1] = v.y; T[row][col + 2] = v.z; T[row][col + 3] = v.w;
    }
    __syncthreads();
    const size_t obase = ((size_t)slab * 64 + ksec * 16) * 512;
#pragma unroll
    for (int r = 0; r < 4; r++) {
        int c = r * 256 + t;
        int kt = c >> 6, lam = c & 63;
        int m = lam & 15, kb = kt * 32 + (lam >> 4) * 8;
        f16x8 h, l;
#pragma unroll
        for (int e = 0; e < 8; e++) {
            float x = T[m][kb + e];
            _Float16 hh = (_Float16)x;
            h[e] = hh;
            l[e] = (_Float16)(x - (float)hh);
        }
        *(f16x8*)(hi + obase + (size_t)c * 8) = h;
        if (lo) *(f16x8*)(lo + obase + (size_t)c * 8) = l;
    }
}

// ---------------- sb[b][l] = sum_h bias[h]*hidden[l][b][h] ----------------
__global__ __launch_bounds__(256) void ksb_kernel(const float* __restrict__ hidden,
                                                  const float* __restrict__ bias,
                                                  float* __restrict__ sb) {
    const int b = blockIdx.x, t = threadIdx.x;
    const int l = t & 63, j = t >> 6;
    const float* hp = hidden + (size_t)l * (B_ * H_) + b * H_ + j * 256;
    const float* bp = bias + j * 256;
    float s = 0.f;
    for (int i = 0; i < 64; i++) {
        float4 h4 = *(const float4*)(hp + i * 4);
        float4 b4 = *(const float4*)(bp + i * 4);
        s += h4.x * b4.x + h4.y * b4.y + h4.z * b4.z + h4.w * b4.w;
    }
    __shared__ float red[256];
    red[t] = s; __syncthreads();
    if (t < 128) red[t] += red[t + 128];
    __syncthreads();
    if (t < 64) sb[b * 64 + t] = red[t] + red[t + 64];
}

// ---------------- kv2: V[b][l][k] = sum_h W[h][k]*hidden[l][b][h] (fp32) -> tiled fp16 hi/lo ----------------
__global__ __launch_bounds__(256) void kv2_kernel(const float* __restrict__ hidden,
                                                  const float* __restrict__ W,
                                                  _Float16* __restrict__ vh,
                                                  _Float16* __restrict__ vl) {
    __shared__ float Ah[64][17];
    __shared__ float Wt[16][64];
    const int b = blockIdx.x;
    const int k0 = blockIdx.y * 64;
    const int t = threadIdx.x;
    const int lt = t & 15, kt = t >> 4;
    float acc[4][4];
#pragma unroll
    for (int i = 0; i < 4; i++)
#pragma unroll
        for (int j = 0; j < 4; j++) acc[i][j] = 0.f;

    const int ar = t >> 2, ac4 = (t & 3) * 4;
    const int wrow = t >> 4, wc4 = (t & 15) * 4;

    for (int h0 = 0; h0 < H_; h0 += 16) {
        float4 av = *(const float4*)(hidden + (size_t)ar * (B_ * H_) + b * H_ + h0 + ac4);
        Ah[ar][ac4 + 0] = av.x; Ah[ar][ac4 + 1] = av.y; Ah[ar][ac4 + 2] = av.z; Ah[ar][ac4 + 3] = av.w;
        *(float4*)&Wt[wrow][wc4] = *(const float4*)(W + (size_t)(h0 + wrow) * K2H + k0 + wc4);
        __syncthreads();
#pragma unroll
        for (int hh = 0; hh < 16; hh++) {
            float a0 = Ah[lt * 4 + 0][hh], a1 = Ah[lt * 4 + 1][hh];
            float a2 = Ah[lt * 4 + 2][hh], a3 = Ah[lt * 4 + 3][hh];
            float4 wv = *(const float4*)&Wt[hh][kt * 4];
            acc[0][0] += a0 * wv.x; acc[0][1] += a0 * wv.y; acc[0][2] += a0 * wv.z; acc[0][3] += a0 * wv.w;
            acc[1][0] += a1 * wv.x; acc[1][1] += a1 * wv.y; acc[1][2] += a1 * wv.z; acc[1][3] += a1 * wv.w;
            acc[2][0] += a2 * wv.x; acc[2][1] += a2 * wv.y; acc[2][2] += a2 * wv.z; acc[2][3] += a2 * wv.w;
            acc[3][0] += a3 * wv.x; acc[3][1] += a3 * wv.y; acc[3][2] += a3 * wv.z; acc[3][3] += a3 * wv.w;
        }
        __syncthreads();
    }
#pragma unroll
    for (int i = 0; i < 4; i++) {
        const int l = lt * 4 + i;
        const int ltile = l >> 4, lam = l & 15;
#pragma unroll
        for (int j = 0; j < 4; j++) {
            const int k = k0 + kt * 4 + j;
            const size_t idx = (((size_t)(b * 4 + ltile) * 64) + (k >> 5)) * 512
                             + (size_t)((((k >> 3) & 3) * 16 + lam) * 8 + (k & 7));
            float v = acc[i][j];
            _Float16 hh = (_Float16)v;
            vh[idx] = hh;
            vl[idx] = (_Float16)(v - (float)hh);
        }
    }
}

// ---------------- k1f: reduced = enc16 @ W16^T + bias -> B-fragment layout [b][64 ht][128 st][512] ----------------
__global__ __launch_bounds__(256) void k1f_kernel(const _Float16* __restrict__ eh,
                                                  const _Float16* __restrict__ wh,
                                                  const float* __restrict__ bias,
                                                  _Float16* __restrict__ redB) {
    __shared__ _Float16 As[8192];
    __shared__ _Float16 Bs[8192];
    const int t = threadIdx.x;
    const int n0 = blockIdx.x * 128, m0 = blockIdx.y * 128;
    const int w = t >> 6, lane = t & 63;
    const int wr = w >> 1, wc = w & 1;
    const int ml = lane & 15, q = lane >> 4;

    f32x4 acc[4][4] = {};
    const bool isA = (w < 2);
    const int cbase = (w & 1) * 8;
    const _Float16* gsrc = isA ? eh : wh;
    const int rtile0 = isA ? (m0 >> 4) : (n0 >> 4);
    _Float16* lds = isA ? As : Bs;

    for (int kt0 = 0; kt0 < 64; kt0 += 2) {
#pragma unroll
        for (int li = 0; li < 8; li++) {
            const int c = cbase + li;
            const size_t goff = ((size_t)(rtile0 + (c >> 1)) * 64 + kt0 + (c & 1)) * 512 + lane * 8;
            gload16(gsrc + goff, lds + c * 512);
        }
        __syncthreads();
#pragma unroll
        for (int kk = 0; kk < 2; kk++) {
            f16x8 af[4], bf[4];
#pragma unroll
            for (int i = 0; i < 4; i++) af[i] = *(const f16x8*)&As[(size_t)(((wr * 4 + i) * 2 + kk) * 512 + lane * 8)];
#pragma unroll
            for (int j = 0; j < 4; j++) bf[j] = *(const f16x8*)&Bs[(size_t)(((wc * 4 + j) * 2 + kk) * 512 + lane * 8)];
#pragma unroll
            for (int i = 0; i < 4; i++)
#pragma unroll
                for (int j = 0; j < 4; j++)
                    acc[i][j] = __builtin_amdgcn_mfma_f32_16x16x32_f16(af[i], bf[j], acc[i][j], 0, 0, 0);
        }
        __syncthreads();
    }
    // epilogue: element (s_local, h) -> B-fragment for k4f
    const int b = m0 >> 12;
    const int m0l = m0 & 4095;
#pragma unroll
    for (int j = 0; j < 4; j++) {
        const int h = n0 + wc * 64 + j * 16 + ml;
        const float bv = bias[h];
        const int htile = h >> 4;
#pragma unroll
        for (int i = 0; i < 4; i++) {
            const int sl = m0l + wr * 64 + i * 16 + q * 4;
            const size_t idx = (((size_t)(b * 64 + htile) * 128) + (sl >> 5)) * 512
                             + (size_t)((((sl >> 3) & 3) * 16 + ml) * 8 + (sl & 7));
            f16x4 v;
#pragma unroll
            for (int r = 0; r < 4; r++) v[r] = (_Float16)(acc[i][j][r] + bv);
            *(f16x4*)(redB + idx) = v;
        }
    }
}

// ---------------- ksf: scores = enc(hi+lo) @ V(hi+lo)^T + sb, split-fp16 ----------------
__global__ __launch_bounds__(256) void ksf_kernel(const _Float16* __restrict__ eh,
                                                  const _Float16* __restrict__ el,
                                                  const _Float16* __restrict__ vh,
                                                  const _Float16* __restrict__ vl,
                                                  const float* __restrict__ sb,
                                                  float* __restrict__ scores) {
    __shared__ _Float16 AH[4096], AL[4096], BH[4096], BL[4096];
    const int t = threadIdx.x;
    const int s0 = blockIdx.x * 64;
    const int b = blockIdx.y;
    const int w = t >> 6, lane = t & 63;
    const int ml = lane & 15, q = lane >> 4;
    f32x4 acc[4] = {};
    const int mt0 = (b * S_ + s0) >> 4;
    const int lt0 = b * 4;
    const _Float16* gsrc = (w == 0) ? eh : (w == 1) ? el : (w == 2) ? vh : vl;
    _Float16* lds = (w == 0) ? AH : (w == 1) ? AL : (w == 2) ? BH : BL;
    const int rt0 = (w < 2) ? mt0 : lt0;

    for (int kt0 = 0; kt0 < 64; kt0 += 2) {
#pragma unroll
        for (int li = 0; li < 8; li++) {
            const size_t goff = ((size_t)(rt0 + (li >> 1)) * 64 + kt0 + (li & 1)) * 512 + lane * 8;
            gload16(gsrc + goff, lds + li * 512);
        }
        __syncthreads();
#pragma unroll
        for (int kk = 0; kk < 2; kk++) {
            f16x8 aH = *(const f16x8*)&AH[(size_t)((w * 2 + kk) * 512 + lane * 8)];
            f16x8 aL = *(const f16x8*)&AL[(size_t)((w * 2 + kk) * 512 + lane * 8)];
#pragma unroll
            for (int j = 0; j < 4; j++) {
                f16x8 bH = *(const f16x8*)&BH[(size_t)((j * 2 + kk) * 512 + lane * 8)];
                f16x8 bL = *(const f16x8*)&BL[(size_t)((j * 2 + kk) * 512 + lane * 8)];
                acc[j] = __builtin_amdgcn_mfma_f32_16x16x32_f16(aH, bH, acc[j], 0, 0, 0);
                acc[j] = __builtin_amdgcn_mfma_f32_16x16x32_f16(aL, bH, acc[j], 0, 0, 0);
                acc[j] = __builtin_amdgcn_mfma_f32_16x16x32_f16(aH, bL, acc[j], 0, 0, 0);
            }
        }
        __syncthreads();
    }
#pragma unroll
    for (int j = 0; j < 4; j++) {
        const int l = j * 16 + ml;
        const float sbv = sb[b * 64 + l];
        const int srow = s0 + w * 16 + q * 4;
#pragma unroll
        for (int r = 0; r < 4; r++)
            scores[(size_t)b * (S_ * L_) + (size_t)(srow + r) * L_ + l] = acc[j][r] + sbv;
    }
}

// ---------------- k4f: context[b][l][h] = sum_s wa[l][s] * redB[s][h]  (MFMA) ----------------
// grid (hc=8, sc=8, b=8); block 256 = 4 waves; BK=64 (2 k-tiles); atomicAdd epilogue
__global__ __launch_bounds__(256) void k4f_kernel(const _Float16* __restrict__ wa,
                                                  const _Float16* __restrict__ redB,
                                                  float* __restrict__ ctx) {
    __shared__ _Float16 ldsA[8 * 512];    // [lt*2+kk][512]
    __shared__ _Float16 ldsB[16 * 512];   // [htl*2+kk][512]
    const int t = threadIdx.x;
    const int hc = blockIdx.x, sc = blockIdx.y, b = blockIdx.z;
    const int w = t >> 6, lane = t & 63;
    const int ml = lane & 15, q = lane >> 4;
    f32x4 acc[4][2] = {};

    for (int kt0 = 0; kt0 < 16; kt0 += 2) {
#pragma unroll
        for (int li = 0; li < 6; li++) {
            const int c = w * 6 + li;
            if (c < 8) {
                const int lt = c >> 1, kk = c & 1;
                const size_t g = (((size_t)(b * 4 + lt) * 128) + sc * 16 + kt0 + kk) * 512 + lane * 8;
                gload16(wa + g, ldsA + c * 512);
            } else {
                const int cc = c - 8;
                const int htl = cc >> 1, kk = cc & 1;
                const size_t g = (((size_t)(b * 64 + hc * 8 + htl) * 128) + sc * 16 + kt0 + kk) * 512 + lane * 8;
                gload16(redB + g, ldsB + cc * 512);
            }
        }
        __syncthreads();
#pragma unroll
        for (int kk = 0; kk < 2; kk++) {
            f16x8 af[4];
#pragma unroll
            for (int lt = 0; lt < 4; lt++) af[lt] = *(const f16x8*)&ldsA[(lt * 2 + kk) * 512 + lane * 8];
#pragma unroll
            for (int jh = 0; jh < 2; jh++) {
                f16x8 bf = *(const f16x8*)&ldsB[((w * 2 + jh) * 2 + kk) * 512 + lane * 8];
#pragma unroll
                for (int lt = 0; lt < 4; lt++)
                    acc[lt][jh] = __builtin_amdgcn_mfma_f32_16x16x32_f16(af[lt], bf, acc[lt][jh], 0, 0, 0);
            }
        }
        __syncthreads();
    }
#pragma unroll
    for (int lt = 0; lt < 4; lt++)
#pragma unroll
        for (int jh = 0; jh < 2; jh++) {
            const int h = hc * 128 + (w * 2 + jh) * 16 + ml;
#pragma unroll
            for (int r = 0; r < 4; r++) {
                const int l = lt * 16 + q * 4 + r;
                atomicAdd(ctx + (((size_t)(b * 64 + l)) << 10) + h, acc[lt][jh][r]);
            }
        }
}

// ================= fallback (round-2) kernels =================

__global__ __launch_bounds__(256) void kv_kernel(const float* __restrict__ hidden,
                                                 const float* __restrict__ W,
                                                 float* __restrict__ V) {
    __shared__ float Ah[64][17];
    __shared__ float Wt[16][64];
    const int b = blockIdx.x;
    const int k0 = blockIdx.y * 64;
    const int t = threadIdx.x;
    const int lt = t & 15, kt = t >> 4;
    float acc[4][4];
#pragma unroll
    for (int i = 0; i < 4; i++)
#pragma unroll
        for (int j = 0; j < 4; j++) acc[i][j] = 0.f;

    const int ar = t >> 2, ac4 = (t & 3) * 4;
    const int wrow = t >> 4, wc4 = (t & 15) * 4;

    for (int h0 = 0; h0 < H_; h0 += 16) {
        float4 av = *(const float4*)(hidden + (size_t)ar * (B_ * H_) + b * H_ + h0 + ac4);
        Ah[ar][ac4 + 0] = av.x; Ah[ar][ac4 + 1] = av.y; Ah[ar][ac4 + 2] = av.z; Ah[ar][ac4 + 3] = av.w;
        *(float4*)&Wt[wrow][wc4] = *(const float4*)(W + (size_t)(h0 + wrow) * K2H + k0 + wc4);
        __syncthreads();
#pragma unroll
        for (int hh = 0; hh < 16; hh++) {
            float a0 = Ah[lt * 4 + 0][hh], a1 = Ah[lt * 4 + 1][hh];
            float a2 = Ah[lt * 4 + 2][hh], a3 = Ah[lt * 4 + 3][hh];
            float4 wv = *(const float4*)&Wt[hh][kt * 4];
            acc[0][0] += a0 * wv.x; acc[0][1] += a0 * wv.y; acc[0][2] += a0 * wv.z; acc[0][3] += a0 * wv.w;
            acc[1][0] += a1 * wv.x; acc[1][1] += a1 * wv.y; acc[1][2] += a1 * wv.z; acc[1][3] += a1 * wv.w;
            acc[2][0] += a2 * wv.x; acc[2][1] += a2 * wv.y; acc[2][2] += a2 * wv.z; acc[2][3] += a2 * wv.w;
            acc[3][0] += a3 * wv.x; acc[3][1] += a3 * wv.y; acc[3][2] += a3 * wv.z; acc[3][3] += a3 * wv.w;
        }
        __syncthreads();
    }
#pragma unroll
    for (int i = 0; i < 4; i++) {
        float4 o; o.x = acc[i][0]; o.y = acc[i][1]; o.z = acc[i][2]; o.w = acc[i][3];
        *(float4*)(V + (size_t)b * (L_ * K2H) + (lt * 4 + i) * K2H + k0 + kt * 4) = o;
    }
}

__global__ __launch_bounds__(256) void k1_kernel(const float* __restrict__ enc,
                                                 const float* __restrict__ W,
                                                 const float* __restrict__ bias,
                                                 _Float16* __restrict__ reduced) {
    __shared__ _Float16 As[128][40];
    __shared__ _Float16 Bs[128][40];
    const int t = threadIdx.x;
    const int n0 = blockIdx.x * 128;
    const int m0 = blockIdx.y * 128;
    const int w = t >> 6, lane = t & 63;
    const int wr = w >> 1, wc = w & 1;
    const int ml = lane & 15, q = lane >> 4;

    f32x4 acc[4][4];
#pragma unroll
    for (int i = 0; i < 4; i++)
#pragma unroll
        for (int j = 0; j < 4; j++) acc[i][j] = (f32x4){0.f, 0.f, 0.f, 0.f};

    const int r0 = t >> 2;
    const int c8 = (t & 3) * 8;

    for (int k0 = 0; k0 < K2H; k0 += 32) {
#pragma unroll
        for (int j = 0; j < 2; ++j) {
            const int row = r0 + 64 * j;
            const float* pa = enc + (size_t)(m0 + row) * K2H + k0 + c8;
            float4 a0 = *(const float4*)pa, a1 = *(const float4*)(pa + 4);
            f16x8 ha;
            ha[0] = (_Float16)a0.x; ha[1] = (_Float16)a0.y; ha[2] = (_Float16)a0.z; ha[3] = (_Float16)a0.w;
            ha[4] = (_Float16)a1.x; ha[5] = (_Float16)a1.y; ha[6] = (_Float16)a1.z; ha[7] = (_Float16)a1.w;
            *(f16x8*)&As[row][c8] = ha;
            const float* pb = W + (size_t)(n0 + row) * K2H + k0 + c8;
            float4 b0 = *(const float4*)pb, b1 = *(const float4*)(pb + 4);
            f16x8 hb;
            hb[0] = (_Float16)b0.x; hb[1] = (_Float16)b0.y; hb[2] = (_Float16)b0.z; hb[3] = (_Float16)b0.w;
            hb[4] = (_Float16)b1.x; hb[5] = (_Float16)b1.y; hb[6] = (_Float16)b1.z; hb[7] = (_Float16)b1.w;
            *(f16x8*)&Bs[row][c8] = hb;
        }
        __syncthreads();
        f16x8 af[4], bf[4];
#pragma unroll
        for (int i = 0; i < 4; i++) af[i] = *(const f16x8*)&As[wr * 64 + i * 16 + ml][q * 8];
#pragma unroll
        for (int j = 0; j < 4; j++) bf[j] = *(const f16x8*)&Bs[wc * 64 + j * 16 + ml][q * 8];
#pragma unroll
        for (int i = 0; i < 4; i++)
#pragma unroll
            for (int j = 0; j < 4; j++)
                acc[i][j] = __builtin_amdgcn_mfma_f32_16x16x32_f16(af[i], bf[j], acc[i][j], 0, 0, 0);
        __syncthreads();
    }
#pragma unroll
    for (int j = 0; j < 4; j++) {
        const int h = n0 + wc * 64 + j * 16 + ml;
        const float bv = bias[h];
#pragma unroll
        for (int i = 0; i < 4; i++) {
            const int srow = m0 + wr * 64 + i * 16 + q * 4;
#pragma unroll
            for (int r = 0; r < 4; r++)
                reduced[(size_t)(srow + r) * H_ + h] = (_Float16)(acc[i][j][r] + bv);
        }
    }
}

__global__ __launch_bounds__(256) void ks_kernel(const float* __restrict__ enc,
                                                 const float* __restrict__ V,
                                                 const float* __restrict__ sb,
                                                 float* __restrict__ scores) {
    __shared__ _Float16 AsH[64][40], AsL[64][40];
    __shared__ _Float16 BsH[64][40], BsL[64][40];
    const int t = threadIdx.x;
    const int s0 = blockIdx.x * 64;
    const int b = blockIdx.y;
    const int w = t >> 6, lane = t & 63;
    const int ml = lane & 15, q = lane >> 4;

    f32x4 acc[4];
#pragma unroll
    for (int j = 0; j < 4; j++) acc[j] = (f32x4){0.f, 0.f, 0.f, 0.f};

    const int r0 = t >> 2, c8 = (t & 3) * 8;

    for (int k0 = 0; k0 < K2H; k0 += 32) {
        {
            const float* pa = enc + (size_t)(b * S_ + s0 + r0) * K2H + k0 + c8;
            float4 a0 = *(const float4*)pa, a1 = *(const float4*)(pa + 4);
            float xv[8] = {a0.x, a0.y, a0.z, a0.w, a1.x, a1.y, a1.z, a1.w};
            f16x8 hh, ll;
#pragma unroll
            for (int e = 0; e < 8; e++) {
                _Float16 hi = (_Float16)xv[e];
                hh[e] = hi;
                ll[e] = (_Float16)(xv[e] - (float)hi);
            }
            *(f16x8*)&AsH[r0][c8] = hh;
            *(f16x8*)&AsL[r0][c8] = ll;
        }
        {
            const float* pb = V + (size_t)b * (L_ * K2H) + (size_t)r0 * K2H + k0 + c8;
            float4 b0 = *(const float4*)pb, b1 = *(const float4*)(pb + 4);
            float xv[8] = {b0.x, b0.y, b0.z, b0.w, b1.x, b1.y, b1.z, b1.w};
            f16x8 hh, ll;
#pragma unroll
            for (int e = 0; e < 8; e++) {
                _Float16 hi = (_Float16)xv[e];
                hh[e] = hi;
                ll[e] = (_Float16)(xv[e] - (float)hi);
            }
            *(f16x8*)&BsH[r0][c8] = hh;
            *(f16x8*)&BsL[r0][c8] = ll;
        }
        __syncthreads();
        f16x8 aH = *(const f16x8*)&AsH[w * 16 + ml][q * 8];
        f16x8 aL = *(const f16x8*)&AsL[w * 16 + ml][q * 8];
#pragma unroll
        for (int j = 0; j < 4; j++) {
            f16x8 bH = *(const f16x8*)&BsH[j * 16 + ml][q * 8];
            f16x8 bL = *(const f16x8*)&BsL[j * 16 + ml][q * 8];
            acc[j] = __builtin_amdgcn_mfma_f32_16x16x32_f16(aH, bH, acc[j], 0, 0, 0);
            acc[j] = __builtin_amdgcn_mfma_f32_16x16x32_f16(aL, bH, acc[j], 0, 0, 0);
            acc[j] = __builtin_amdgcn_mfma_f32_16x16x32_f16(aH, bL, acc[j], 0, 0, 0);
        }
        __syncthreads();
    }
#pragma unroll
    for (int j = 0; j < 4; j++) {
        const int l = j * 16 + ml;
        const float sbv = sb[b * 64 + l];
        const int srow = s0 + w * 16 + q * 4;
#pragma unroll
        for (int r = 0; r < 4; r++)
            scores[(size_t)b * (S_ * L_) + (size_t)(srow + r) * L_ + l] = acc[j][r] + sbv;
    }
}

__global__ __launch_bounds__(256) void k4_kernel(const float* __restrict__ wbuf,
                                                 const _Float16* __restrict__ reduced,
                                                 float* __restrict__ ctx) {
    __shared__ float Ws[64][64];
    __shared__ _Float16 Rs[64][256];
    const int t = threadIdx.x;
    const int b = blockIdx.x, ht = blockIdx.y, sc = blockIdx.z;
    const int h = ht * 256 + t;
    float acc[64];
#pragma unroll
    for (int l = 0; l < 64; l++) acc[l] = 0.f;

    for (int cc = 0; cc < 4; ++cc) {
        const int sbase = sc * 256 + cc * 64;
#pragma unroll
        for (int j = 0; j < 4; j++) {
            int c = t + 256 * j;
            int row = c >> 4, c4 = (c & 15) * 4;
            *(float4*)&Ws[row][c4] =
                *(const float4*)(wbuf + (size_t)b * (S_ * L_) + (size_t)(sbase + row) * L_ + c4);
        }
#pragma unroll
        for (int j = 0; j < 8; j++) {
            int c = t + 256 * j;
            int row = c >> 5, ch = (c & 31) * 8;
            *(uint4*)&Rs[row][ch] =
                *(const uint4*)(reduced + (size_t)(b * S_ + sbase + row) * H_ + ht * 256 + ch);
        }
        __syncthreads();
        for (int ss = 0; ss < 64; ++ss) {
            float r = (float)Rs[ss][t];
            const float4* wr = (const float4*)&Ws[ss][0];
#pragma unroll
            for (int u = 0; u < 16; u++) {
                float4 wv = wr[u];
                acc[u * 4 + 0] += wv.x * r;
                acc[u * 4 + 1] += wv.y * r;
                acc[u * 4 + 2] += wv.z * r;
                acc[u * 4 + 3] += wv.w * r;
            }
        }
        __syncthreads();
    }
#pragma unroll
    for (int l = 0; l < 64; l++)
        atomicAdd(ctx + (size_t)((b * 64 + l) << 10) + h, acc[l]);
}

// ================= shared (both paths) =================

__global__ __launch_bounds__(256) void k3a_kernel(const float* __restrict__ scores,
                                                  float* __restrict__ partM,
                                                  float* __restrict__ partD) {
    const int b = blockIdx.x, chunk = blockIdx.y;
    const int t = threadIdx.x;
    const int l = t & 63, si = t >> 6;
    const float* p = scores + (size_t)b * (S_ * L_) + (size_t)(chunk * 256 + si * 64) * L_ + l;
    float m = -__builtin_inff(), d = 0.f;
    for (int i = 0; i < 64; i++) {
        float x = p[i * 64];
        if (x > m) { d = d * __expf(m - x) + 1.f; m = x; }
        else d += __expf(x - m);
    }
    __shared__ float sm[256], sd[256];
    sm[t] = m; sd[t] = d; __syncthreads();
    if (t < 128) {
        float m2 = sm[t + 128], d2 = sd[t + 128];
        if (m2 > sm[t]) { sd[t] = sd[t] * __expf(sm[t] - m2) + d2; sm[t] = m2; }
        else sd[t] += d2 * __expf(m2 - sm[t]);
    }
    __syncthreads();
    if (t < 64) {
        float m1 = sm[t], d1 = sd[t], m2 = sm[t + 64], d2 = sd[t + 64];
        if (m2 > m1) { d1 = d1 * __expf(m1 - m2) + d2; m1 = m2; }
        else d1 += d2 * __expf(m2 - m1);
        partM[(b * 16 + chunk) * 64 + t] = m1;
        partD[(b * 16 + chunk) * 64 + t] = d1;
    }
}

__global__ __launch_bounds__(512) void k3b_kernel(const float* __restrict__ partM,
                                                  const float* __restrict__ partD,
                                                  float* __restrict__ fm,
                                                  float* __restrict__ fdinv) {
    const int t = threadIdx.x;
    const int b = t >> 6, l = t & 63;
    float m = -__builtin_inff(), d = 0.f;
    for (int c = 0; c < 16; c++) {
        float pm = partM[(b * 16 + c) * 64 + l];
        float pd = partD[(b * 16 + c) * 64 + l];
        if (pm > m) { d = d * __expf(m - pm) + pd; m = pm; }
        else d += pd * __expf(pm - m);
    }
    fm[t] = m;
    fdinv[t] = 1.0f / d;
}

// k3c: weights = exp(x-m)*inv_d (in place fp32) + optional fp16 A-fragment transposed copy
__global__ __launch_bounds__(256) void k3c_kernel(float* __restrict__ wbuf,
                                                  const float* __restrict__ fm,
                                                  const float* __restrict__ fdinv,
                                                  _Float16* __restrict__ watile) {
    const int base = (blockIdx.x * 256 + threadIdx.x) * 8;
    const int b = base >> 18, l0 = base & 63;
    const int s = (base >> 6) & 4095;
    float4 m0 = *(const float4*)(fm + b * 64 + l0);
    float4 m1 = *(const float4*)(fm + b * 64 + l0 + 4);
    float4 i0 = *(const float4*)(fdinv + b * 64 + l0);
    float4 i1 = *(const float4*)(fdinv + b * 64 + l0 + 4);
    float4 x0 = *(const float4*)(wbuf + base);
    float4 x1 = *(const float4*)(wbuf + base + 4);
    float y[8];
    y[0] = __expf(x0.x - m0.x) * i0.x; y[1] = __expf(x0.y - m0.y) * i0.y;
    y[2] = __expf(x0.z - m0.z) * i0.z; y[3] = __expf(x0.w - m0.w) * i0.w;
    y[4] = __expf(x1.x - m1.x) * i1.x; y[5] = __expf(x1.y - m1.y) * i1.y;
    y[6] = __expf(x1.z - m1.z) * i1.z; y[7] = __expf(x1.w - m1.w) * i1.w;
    float4 o0 = {y[0], y[1], y[2], y[3]}, o1 = {y[4], y[5], y[6], y[7]};
    *(float4*)(wbuf + base) = o0;
    *(float4*)(wbuf + base + 4) = o1;
    if (watile) {
        // A-fragment (m=l, k=s) for k4f: [b][4 lt][128 st][512]
        const size_t tbase = (((size_t)(b * 4 + (l0 >> 4)) * 128) + (s >> 5)) * 512 + (size_t)(s & 7);
        const int lane_lo = ((s >> 3) & 3) * 16;
#pragma unroll
        for (int e = 0; e < 8; e++) {
            const int l = l0 + e;
            watile[tbase + (size_t)(lane_lo + (l & 15)) * 8] = (_Float16)y[e];
        }
    }
}

extern "C" void kernel_launch(void* const* d_in, const int* in_sizes, int n_in,
                              void* d_out, int out_size, void* d_ws, size_t ws_size,
                              hipStream_t stream) {
    const float* hidden = (const float*)d_in[0];
    const float* enc    = (const float*)d_in[1];
    const float* W      = (const float*)d_in[2];
    const float* bias   = (const float*)d_in[3];

    float* ctx  = (float*)d_out;
    float* wbuf = (float*)d_out + (B_ * L_ * H_);

    char* ws = (char*)d_ws;
    const size_t NEED_FAST = 344004608;

    hipMemsetAsync(ctx, 0, (size_t)B_ * L_ * H_ * sizeof(float), stream);

    if (ws_size >= NEED_FAST) {
        _Float16* enc_hi  = (_Float16*)ws;                          // 134217728 B
        _Float16* enc_lo  = (_Float16*)(ws + 134217728);            // 134217728 B
        _Float16* redB    = (_Float16*)(ws + 268435456);            //  67108864 B (B-fragment reduced)
        _Float16* w16     = (_Float16*)(ws + 335544320);            //   4194304 B
        _Float16* vh      = (_Float16*)(ws + 339738624);            //   2097152 B
        _Float16* vl      = (_Float16*)(ws + 341835776);            //   2097152 B
        _Float16* watile  = vh;   // 4 MB, aliases vh+vl (dead after ksf; k3c writes after ksf)
        float* partM = (float*)(ws + 343932928);
        float* partD = partM + 8 * 16 * 64;
        float* fm    = partD + 8 * 16 * 64;
        float* fdinv = fm + 512;
        float* sb    = fdinv + 512;

        kcast_kernel<<<dim3(2048, 4), 256, 0, stream>>>(enc, enc_hi, enc_lo);
        kcast_kernel<<<dim3(64, 4), 256, 0, stream>>>(W, w16, (_Float16*)nullptr);
        ksb_kernel<<<8, 256, 0, stream>>>(hidden, bias, sb);
        kv2_kernel<<<dim3(8, 32), 256, 0, stream>>>(hidden, W, vh, vl);
        k1f_kernel<<<dim3(8, 256), 256, 0, stream>>>(enc_hi, w16, bias, redB);
        ksf_kernel<<<dim3(64, 8), 256, 0, stream>>>(enc_hi, enc_lo, vh, vl, sb, wbuf);
        k3a_kernel<<<dim3(8, 16), 256, 0, stream>>>(wbuf, partM, partD);
        k3b_kernel<<<1, 512, 0, stream>>>(partM, partD, fm, fdinv);
        k3c_kernel<<<2097152 / (256 * 8), 256, 0, stream>>>(wbuf, fm, fdinv, watile);
        k4f_kernel<<<dim3(8, 8, 8), 256, 0, stream>>>(watile, redB, ctx);
    } else {
        _Float16* reduced = (_Float16*)ws;                       // 67108864 B
        float* V     = (float*)(ws + 67108864);                  //  4194304 B
        float* partM = (float*)(ws + 71303168);
        float* partD = partM + 8 * 16 * 64;
        float* fm    = partD + 8 * 16 * 64;
        float* fdinv = fm + 512;
        float* sb    = fdinv + 512;

        ksb_kernel<<<8, 256, 0, stream>>>(hidden, bias, sb);
        kv_kernel<<<dim3(8, 32), 256, 0, stream>>>(hidden, W, V);
        k1_kernel<<<dim3(8, 256), 256, 0, stream>>>(enc, W, bias, reduced);
        ks_kernel<<<dim3(64, 8), 256, 0, stream>>>(enc, V, sb, wbuf);
        k3a_kernel<<<dim3(8, 16), 256, 0, stream>>>(wbuf, partM, partD);
        k3b_kernel<<<1, 512, 0, stream>>>(partM, partD, fm, fdinv);
        k3c_kernel<<<2097152 / (256 * 8), 256, 0, stream>>>(wbuf, fm, fdinv, (_Float16*)nullptr);
        k4_kernel<<<dim3(8, 4, 16), 256, 0, stream>>>(wbuf, reduced, ctx);
    }
}

// Round 5
// 778.429 us; speedup vs baseline: 1.2674x; 1.0155x over previous
//
#include <hip/hip_runtime.h>

// DotProductAttention: H=1024, B=8, S=4096, L=64
// inputs: d_in[0]=hidden f32 [L,B,H], d_in[1]=enc f32 [B,S,2H], d_in[2]=W f32 [H,2H], d_in[3]=bias f32 [H]
// out: context f32 [B,L,H] (524288) then weights f32 [B,S,L] (2097152)
//
// FAST path (ws_size >= 209784832):
//   kv2: V=W^T·hidden fp32 exact -> fp16 hi/lo fragment planes
//   kcs: enc fp32 -> fragment fp16 hi (stored) ; scores = enc(hi+lo)@V(hi+lo)^T fused
//        (wave w holds complete A-fragment of ktile r*4+w in regs -> direct MFMA)
//   k1f: reduced = enc_hi @ w16^T + bias (MFMA, global_load_lds, XCD-swizzled grid)
//   softmax (k3a/b/c, exact fp32; bias·hidden term dropped: softmax shift-invariant)
//   k4f: context = weights^T @ reduced (MFMA on fragment-tiled operands)
// FALLBACK path: round-2 kernels verbatim (known-pass, 986 us).

#define H_ 1024
#define B_ 8
#define S_ 4096
#define L_ 64
#define K2H 2048
#define M_ 32768

typedef _Float16 f16x8 __attribute__((ext_vector_type(8)));
typedef _Float16 f16x4 __attribute__((ext_vector_type(4)));
typedef float f32x4 __attribute__((ext_vector_type(4)));

typedef const __attribute__((address_space(1))) void* gas_ptr_t;
typedef __attribute__((address_space(3))) void* las_ptr_t;

__device__ __forceinline__ void gload16(const _Float16* g, _Float16* l) {
    __builtin_amdgcn_global_load_lds((gas_ptr_t)g, (las_ptr_t)l, 16, 0, 0);
}

// Fragment layout (A/B operand of mfma 16x16x32 f16), rows=m-or-n, k:
//   tile = (row/16, k/32); lane = ((k%32)/8)*16 + row%16, elem = k%8
//   linear = (tile_row*NTK + tile_k)*512 + lane*8 + elem

// ---------------- kcast: fp32 [rows][2048] -> fragment-tiled fp16 hi (+ optional lo) ----------------
__global__ __launch_bounds__(256) void kcast_kernel(const float* __restrict__ src,
                                                    _Float16* __restrict__ hi,
                                                    _Float16* __restrict__ lo) {
    __shared__ float T[16][516];
    const int t = threadIdx.x;
    const int slab = blockIdx.x, ksec = blockIdx.y;
    const float* sp = src + (size_t)slab * 16 * K2H + ksec * 512;
#pragma unroll
    for (int r = 0; r < 8; r++) {
        int lin = r * 1024 + t * 4;
        int row = lin >> 9, col = lin & 511;
        float4 v = *(const float4*)(sp + (size_t)row * K2H + col);
        T[row][col] = v.x; T[row][col + 1] = v.y; T[row][col + 2] = v.z; T[row][col + 3] = v.w;
    }
    __syncthreads();
    const size_t obase = ((size_t)slab * 64 + ksec * 16) * 512;
#pragma unroll
    for (int r = 0; r < 4; r++) {
        int c = r * 256 + t;
        int kt = c >> 6, lam = c & 63;
        int m = lam & 15, kb = kt * 32 + (lam >> 4) * 8;
        f16x8 h, l;
#pragma unroll
        for (int e = 0; e < 8; e++) {
            float x = T[m][kb + e];
            _Float16 hh = (_Float16)x;
            h[e] = hh;
            l[e] = (_Float16)(x - (float)hh);
        }
        *(f16x8*)(hi + obase + (size_t)c * 8) = h;
        if (lo) *(f16x8*)(lo + obase + (size_t)c * 8) = l;
    }
}

// ---------------- kcs: enc cast (hi plane stored) + fused score GEMM ----------------
// grid 2048 (slab = 16 enc rows); block 256 = 4 waves.
// Wave w at step r holds the full A-fragment of local ktile r*4+w in registers;
// ksec loop accumulates all 64 ktiles (16 per wave), LDS-reduce, direct score write.
__global__ __launch_bounds__(256) void kcs_kernel(const float* __restrict__ enc,
                                                  _Float16* __restrict__ hi,
                                                  const _Float16* __restrict__ vh,
                                                  const _Float16* __restrict__ vl,
                                                  float* __restrict__ scores) {
    __shared__ float T[16][516];
    __shared__ float P[4][16][66];
    const int t = threadIdx.x;
    const int slab = blockIdx.x;
    const int b = slab >> 8;
    const int w = t >> 6, lane = t & 63;
    const int ml = lane & 15, q = lane >> 4;
    f32x4 acc[4] = {};

    for (int ksec = 0; ksec < 4; ksec++) {
        const float* sp = enc + (size_t)slab * (16 * K2H) + ksec * 512;
#pragma unroll
        for (int r = 0; r < 8; r++) {
            int lin = r * 1024 + t * 4;
            int row = lin >> 9, col = lin & 511;
            float4 v = *(const float4*)(sp + (size_t)row * K2H + col);
            T[row][col] = v.x; T[row][col + 1] = v.y; T[row][col + 2] = v.z; T[row][col + 3] = v.w;
        }
        __syncthreads();
        const size_t obase = ((size_t)slab * 64 + ksec * 16) * 512;
#pragma unroll
        for (int r = 0; r < 4; r++) {
            const int c = r * 256 + t;
            const int ktl = r * 4 + w;            // == c>>6
            const int kb = ktl * 32 + q * 8;      // lam == lane here
            f16x8 h, l;
#pragma unroll
            for (int e = 0; e < 8; e++) {
                float x = T[ml][kb + e];
                _Float16 hh = (_Float16)x;
                h[e] = hh;
                l[e] = (_Float16)(x - (float)hh);
            }
            *(f16x8*)(hi + obase + (size_t)c * 8) = h;
            // fused score MFMA: ktile global = ksec*16 + ktl
            const int ktg = ksec * 16 + ktl;
            const size_t vbase = (((size_t)(b * 4) * 64) + ktg) * 512 + (size_t)lane * 8;
#pragma unroll
            for (int lt = 0; lt < 4; lt++) {
                f16x8 bH = *(const f16x8*)(vh + vbase + (size_t)lt * 32768);
                f16x8 bL = *(const f16x8*)(vl + vbase + (size_t)lt * 32768);
                acc[lt] = __builtin_amdgcn_mfma_f32_16x16x32_f16(h, bH, acc[lt], 0, 0, 0);
                acc[lt] = __builtin_amdgcn_mfma_f32_16x16x32_f16(l, bH, acc[lt], 0, 0, 0);
                acc[lt] = __builtin_amdgcn_mfma_f32_16x16x32_f16(h, bL, acc[lt], 0, 0, 0);
            }
        }
        __syncthreads();   // T reads done before next ksec overwrite
    }
    // cross-wave reduce: partials -> scores
#pragma unroll
    for (int lt = 0; lt < 4; lt++)
#pragma unroll
        for (int r = 0; r < 4; r++)
            P[w][q * 4 + r][lt * 16 + ml] = acc[lt][r];
    __syncthreads();
    const int s0 = (slab & 255) * 16;
#pragma unroll
    for (int u = 0; u < 4; u++) {
        const int idx = u * 256 + t;
        const int srow = idx >> 6, l = idx & 63;
        float v = P[0][srow][l] + P[1][srow][l] + P[2][srow][l] + P[3][srow][l];
        scores[(size_t)b * (S_ * L_) + (size_t)(s0 + srow) * L_ + l] = v;
    }
}

// ---------------- kv2: V[b][l][k] = sum_h W[h][k]*hidden[l][b][h] (fp32) -> tiled fp16 hi/lo ----------------
__global__ __launch_bounds__(256) void kv2_kernel(const float* __restrict__ hidden,
                                                  const float* __restrict__ W,
                                                  _Float16* __restrict__ vh,
                                                  _Float16* __restrict__ vl) {
    __shared__ float Ah[64][17];
    __shared__ float Wt[16][64];
    const int b = blockIdx.x;
    const int k0 = blockIdx.y * 64;
    const int t = threadIdx.x;
    const int lt = t & 15, kt = t >> 4;
    float acc[4][4];
#pragma unroll
    for (int i = 0; i < 4; i++)
#pragma unroll
        for (int j = 0; j < 4; j++) acc[i][j] = 0.f;

    const int ar = t >> 2, ac4 = (t & 3) * 4;
    const int wrow = t >> 4, wc4 = (t & 15) * 4;

    for (int h0 = 0; h0 < H_; h0 += 16) {
        float4 av = *(const float4*)(hidden + (size_t)ar * (B_ * H_) + b * H_ + h0 + ac4);
        Ah[ar][ac4 + 0] = av.x; Ah[ar][ac4 + 1] = av.y; Ah[ar][ac4 + 2] = av.z; Ah[ar][ac4 + 3] = av.w;
        *(float4*)&Wt[wrow][wc4] = *(const float4*)(W + (size_t)(h0 + wrow) * K2H + k0 + wc4);
        __syncthreads();
#pragma unroll
        for (int hh = 0; hh < 16; hh++) {
            float a0 = Ah[lt * 4 + 0][hh], a1 = Ah[lt * 4 + 1][hh];
            float a2 = Ah[lt * 4 + 2][hh], a3 = Ah[lt * 4 + 3][hh];
            float4 wv = *(const float4*)&Wt[hh][kt * 4];
            acc[0][0] += a0 * wv.x; acc[0][1] += a0 * wv.y; acc[0][2] += a0 * wv.z; acc[0][3] += a0 * wv.w;
            acc[1][0] += a1 * wv.x; acc[1][1] += a1 * wv.y; acc[1][2] += a1 * wv.z; acc[1][3] += a1 * wv.w;
            acc[2][0] += a2 * wv.x; acc[2][1] += a2 * wv.y; acc[2][2] += a2 * wv.z; acc[2][3] += a2 * wv.w;
            acc[3][0] += a3 * wv.x; acc[3][1] += a3 * wv.y; acc[3][2] += a3 * wv.z; acc[3][3] += a3 * wv.w;
        }
        __syncthreads();
    }
#pragma unroll
    for (int i = 0; i < 4; i++) {
        const int l = lt * 4 + i;
        const int ltile = l >> 4, lam = l & 15;
#pragma unroll
        for (int j = 0; j < 4; j++) {
            const int k = k0 + kt * 4 + j;
            const size_t idx = (((size_t)(b * 4 + ltile) * 64) + (k >> 5)) * 512
                             + (size_t)((((k >> 3) & 3) * 16 + lam) * 8 + (k & 7));
            float v = acc[i][j];
            _Float16 hh = (_Float16)v;
            vh[idx] = hh;
            vl[idx] = (_Float16)(v - (float)hh);
        }
    }
}

// ---------------- k1f: reduced = enc16 @ W16^T + bias -> B-fragment layout [b][64 ht][128 st][512] ----------------
// 1D grid 2048, XCD-swizzled: 8 same-m blocks -> same XCD (bi%8 round-robin heuristic)
__global__ __launch_bounds__(256) void k1f_kernel(const _Float16* __restrict__ eh,
                                                  const _Float16* __restrict__ wh,
                                                  const float* __restrict__ bias,
                                                  _Float16* __restrict__ redB) {
    __shared__ _Float16 As[8192];
    __shared__ _Float16 Bs[8192];
    const int t = threadIdx.x;
    const int bi = blockIdx.x;
    const int m_idx = (bi & 7) * 32 + (bi >> 6);
    const int n_idx = (bi >> 3) & 7;
    const int n0 = n_idx * 128, m0 = m_idx * 128;
    const int w = t >> 6, lane = t & 63;
    const int wr = w >> 1, wc = w & 1;
    const int ml = lane & 15, q = lane >> 4;

    f32x4 acc[4][4] = {};
    const bool isA = (w < 2);
    const int cbase = (w & 1) * 8;
    const _Float16* gsrc = isA ? eh : wh;
    const int rtile0 = isA ? (m0 >> 4) : (n0 >> 4);
    _Float16* lds = isA ? As : Bs;

    for (int kt0 = 0; kt0 < 64; kt0 += 2) {
#pragma unroll
        for (int li = 0; li < 8; li++) {
            const int c = cbase + li;
            const size_t goff = ((size_t)(rtile0 + (c >> 1)) * 64 + kt0 + (c & 1)) * 512 + lane * 8;
            gload16(gsrc + goff, lds + c * 512);
        }
        __syncthreads();
#pragma unroll
        for (int kk = 0; kk < 2; kk++) {
            f16x8 af[4], bf[4];
#pragma unroll
            for (int i = 0; i < 4; i++) af[i] = *(const f16x8*)&As[(size_t)(((wr * 4 + i) * 2 + kk) * 512 + lane * 8)];
#pragma unroll
            for (int j = 0; j < 4; j++) bf[j] = *(const f16x8*)&Bs[(size_t)(((wc * 4 + j) * 2 + kk) * 512 + lane * 8)];
#pragma unroll
            for (int i = 0; i < 4; i++)
#pragma unroll
                for (int j = 0; j < 4; j++)
                    acc[i][j] = __builtin_amdgcn_mfma_f32_16x16x32_f16(af[i], bf[j], acc[i][j], 0, 0, 0);
        }
        __syncthreads();
    }
    // epilogue: element (s_local, h) -> B-fragment for k4f
    const int b = m0 >> 12;
    const int m0l = m0 & 4095;
#pragma unroll
    for (int j = 0; j < 4; j++) {
        const int h = n0 + wc * 64 + j * 16 + ml;
        const float bv = bias[h];
        const int htile = h >> 4;
#pragma unroll
        for (int i = 0; i < 4; i++) {
            const int sl = m0l + wr * 64 + i * 16 + q * 4;
            const size_t idx = (((size_t)(b * 64 + htile) * 128) + (sl >> 5)) * 512
                             + (size_t)((((sl >> 3) & 3) * 16 + ml) * 8 + (sl & 7));
            f16x4 v;
#pragma unroll
            for (int r = 0; r < 4; r++) v[r] = (_Float16)(acc[i][j][r] + bv);
            *(f16x4*)(redB + idx) = v;
        }
    }
}

// ---------------- k4f: context[b][l][h] = sum_s wa[l][s] * redB[s][h]  (MFMA) ----------------
__global__ __launch_bounds__(256) void k4f_kernel(const _Float16* __restrict__ wa,
                                                  const _Float16* __restrict__ redB,
                                                  float* __restrict__ ctx) {
    __shared__ _Float16 ldsA[8 * 512];
    __shared__ _Float16 ldsB[16 * 512];
    const int t = threadIdx.x;
    const int hc = blockIdx.x, sc = blockIdx.y, b = blockIdx.z;
    const int w = t >> 6, lane = t & 63;
    const int ml = lane & 15, q = lane >> 4;
    f32x4 acc[4][2] = {};

    for (int kt0 = 0; kt0 < 16; kt0 += 2) {
#pragma unroll
        for (int li = 0; li < 6; li++) {
            const int c = w * 6 + li;
            if (c < 8) {
                const int lt = c >> 1, kk = c & 1;
                const size_t g = (((size_t)(b * 4 + lt) * 128) + sc * 16 + kt0 + kk) * 512 + lane * 8;
                gload16(wa + g, ldsA + c * 512);
            } else {
                const int cc = c - 8;
                const int htl = cc >> 1, kk = cc & 1;
                const size_t g = (((size_t)(b * 64 + hc * 8 + htl) * 128) + sc * 16 + kt0 + kk) * 512 + lane * 8;
                gload16(redB + g, ldsB + cc * 512);
            }
        }
        __syncthreads();
#pragma unroll
        for (int kk = 0; kk < 2; kk++) {
            f16x8 af[4];
#pragma unroll
            for (int lt = 0; lt < 4; lt++) af[lt] = *(const f16x8*)&ldsA[(lt * 2 + kk) * 512 + lane * 8];
#pragma unroll
            for (int jh = 0; jh < 2; jh++) {
                f16x8 bf = *(const f16x8*)&ldsB[((w * 2 + jh) * 2 + kk) * 512 + lane * 8];
#pragma unroll
                for (int lt = 0; lt < 4; lt++)
                    acc[lt][jh] = __builtin_amdgcn_mfma_f32_16x16x32_f16(af[lt], bf, acc[lt][jh], 0, 0, 0);
            }
        }
        __syncthreads();
    }
#pragma unroll
    for (int lt = 0; lt < 4; lt++)
#pragma unroll
        for (int jh = 0; jh < 2; jh++) {
            const int h = hc * 128 + (w * 2 + jh) * 16 + ml;
#pragma unroll
            for (int r = 0; r < 4; r++) {
                const int l = lt * 16 + q * 4 + r;
                atomicAdd(ctx + (((size_t)(b * 64 + l)) << 10) + h, acc[lt][jh][r]);
            }
        }
}

// ================= fallback (round-2) kernels =================

__global__ __launch_bounds__(256) void ksb_kernel(const float* __restrict__ hidden,
                                                  const float* __restrict__ bias,
                                                  float* __restrict__ sb) {
    const int b = blockIdx.x, t = threadIdx.x;
    const int l = t & 63, j = t >> 6;
    const float* hp = hidden + (size_t)l * (B_ * H_) + b * H_ + j * 256;
    const float* bp = bias + j * 256;
    float s = 0.f;
    for (int i = 0; i < 64; i++) {
        float4 h4 = *(const float4*)(hp + i * 4);
        float4 b4 = *(const float4*)(bp + i * 4);
        s += h4.x * b4.x + h4.y * b4.y + h4.z * b4.z + h4.w * b4.w;
    }
    __shared__ float red[256];
    red[t] = s; __syncthreads();
    if (t < 128) red[t] += red[t + 128];
    __syncthreads();
    if (t < 64) sb[b * 64 + t] = red[t] + red[t + 64];
}

__global__ __launch_bounds__(256) void kv_kernel(const float* __restrict__ hidden,
                                                 const float* __restrict__ W,
                                                 float* __restrict__ V) {
    __shared__ float Ah[64][17];
    __shared__ float Wt[16][64];
    const int b = blockIdx.x;
    const int k0 = blockIdx.y * 64;
    const int t = threadIdx.x;
    const int lt = t & 15, kt = t >> 4;
    float acc[4][4];
#pragma unroll
    for (int i = 0; i < 4; i++)
#pragma unroll
        for (int j = 0; j < 4; j++) acc[i][j] = 0.f;

    const int ar = t >> 2, ac4 = (t & 3) * 4;
    const int wrow = t >> 4, wc4 = (t & 15) * 4;

    for (int h0 = 0; h0 < H_; h0 += 16) {
        float4 av = *(const float4*)(hidden + (size_t)ar * (B_ * H_) + b * H_ + h0 + ac4);
        Ah[ar][ac4 + 0] = av.x; Ah[ar][ac4 + 1] = av.y; Ah[ar][ac4 + 2] = av.z; Ah[ar][ac4 + 3] = av.w;
        *(float4*)&Wt[wrow][wc4] = *(const float4*)(W + (size_t)(h0 + wrow) * K2H + k0 + wc4);
        __syncthreads();
#pragma unroll
        for (int hh = 0; hh < 16; hh++) {
            float a0 = Ah[lt * 4 + 0][hh], a1 = Ah[lt * 4 + 1][hh];
            float a2 = Ah[lt * 4 + 2][hh], a3 = Ah[lt * 4 + 3][hh];
            float4 wv = *(const float4*)&Wt[hh][kt * 4];
            acc[0][0] += a0 * wv.x; acc[0][1] += a0 * wv.y; acc[0][2] += a0 * wv.z; acc[0][3] += a0 * wv.w;
            acc[1][0] += a1 * wv.x; acc[1][1] += a1 * wv.y; acc[1][2] += a1 * wv.z; acc[1][3] += a1 * wv.w;
            acc[2][0] += a2 * wv.x; acc[2][1] += a2 * wv.y; acc[2][2] += a2 * wv.z; acc[2][3] += a2 * wv.w;
            acc[3][0] += a3 * wv.x; acc[3][1] += a3 * wv.y; acc[3][2] += a3 * wv.z; acc[3][3] += a3 * wv.w;
        }
        __syncthreads();
    }
#pragma unroll
    for (int i = 0; i < 4; i++) {
        float4 o; o.x = acc[i][0]; o.y = acc[i][1]; o.z = acc[i][2]; o.w = acc[i][3];
        *(float4*)(V + (size_t)b * (L_ * K2H) + (lt * 4 + i) * K2H + k0 + kt * 4) = o;
    }
}

__global__ __launch_bounds__(256) void k1_kernel(const float* __restrict__ enc,
                                                 const float* __restrict__ W,
                                                 const float* __restrict__ bias,
                                                 _Float16* __restrict__ reduced) {
    __shared__ _Float16 As[128][40];
    __shared__ _Float16 Bs[128][40];
    const int t = threadIdx.x;
    const int n0 = blockIdx.x * 128;
    const int m0 = blockIdx.y * 128;
    const int w = t >> 6, lane = t & 63;
    const int wr = w >> 1, wc = w & 1;
    const int ml = lane & 15, q = lane >> 4;

    f32x4 acc[4][4];
#pragma unroll
    for (int i = 0; i < 4; i++)
#pragma unroll
        for (int j = 0; j < 4; j++) acc[i][j] = (f32x4){0.f, 0.f, 0.f, 0.f};

    const int r0 = t >> 2;
    const int c8 = (t & 3) * 8;

    for (int k0 = 0; k0 < K2H; k0 += 32) {
#pragma unroll
        for (int j = 0; j < 2; ++j) {
            const int row = r0 + 64 * j;
            const float* pa = enc + (size_t)(m0 + row) * K2H + k0 + c8;
            float4 a0 = *(const float4*)pa, a1 = *(const float4*)(pa + 4);
            f16x8 ha;
            ha[0] = (_Float16)a0.x; ha[1] = (_Float16)a0.y; ha[2] = (_Float16)a0.z; ha[3] = (_Float16)a0.w;
            ha[4] = (_Float16)a1.x; ha[5] = (_Float16)a1.y; ha[6] = (_Float16)a1.z; ha[7] = (_Float16)a1.w;
            *(f16x8*)&As[row][c8] = ha;
            const float* pb = W + (size_t)(n0 + row) * K2H + k0 + c8;
            float4 b0 = *(const float4*)pb, b1 = *(const float4*)(pb + 4);
            f16x8 hb;
            hb[0] = (_Float16)b0.x; hb[1] = (_Float16)b0.y; hb[2] = (_Float16)b0.z; hb[3] = (_Float16)b0.w;
            hb[4] = (_Float16)b1.x; hb[5] = (_Float16)b1.y; hb[6] = (_Float16)b1.z; hb[7] = (_Float16)b1.w;
            *(f16x8*)&Bs[row][c8] = hb;
        }
        __syncthreads();
        f16x8 af[4], bf[4];
#pragma unroll
        for (int i = 0; i < 4; i++) af[i] = *(const f16x8*)&As[wr * 64 + i * 16 + ml][q * 8];
#pragma unroll
        for (int j = 0; j < 4; j++) bf[j] = *(const f16x8*)&Bs[wc * 64 + j * 16 + ml][q * 8];
#pragma unroll
        for (int i = 0; i < 4; i++)
#pragma unroll
            for (int j = 0; j < 4; j++)
                acc[i][j] = __builtin_amdgcn_mfma_f32_16x16x32_f16(af[i], bf[j], acc[i][j], 0, 0, 0);
        __syncthreads();
    }
#pragma unroll
    for (int j = 0; j < 4; j++) {
        const int h = n0 + wc * 64 + j * 16 + ml;
        const float bv = bias[h];
#pragma unroll
        for (int i = 0; i < 4; i++) {
            const int srow = m0 + wr * 64 + i * 16 + q * 4;
#pragma unroll
            for (int r = 0; r < 4; r++)
                reduced[(size_t)(srow + r) * H_ + h] = (_Float16)(acc[i][j][r] + bv);
        }
    }
}

__global__ __launch_bounds__(256) void ks_kernel(const float* __restrict__ enc,
                                                 const float* __restrict__ V,
                                                 const float* __restrict__ sb,
                                                 float* __restrict__ scores) {
    __shared__ _Float16 AsH[64][40], AsL[64][40];
    __shared__ _Float16 BsH[64][40], BsL[64][40];
    const int t = threadIdx.x;
    const int s0 = blockIdx.x * 64;
    const int b = blockIdx.y;
    const int w = t >> 6, lane = t & 63;
    const int ml = lane & 15, q = lane >> 4;

    f32x4 acc[4];
#pragma unroll
    for (int j = 0; j < 4; j++) acc[j] = (f32x4){0.f, 0.f, 0.f, 0.f};

    const int r0 = t >> 2, c8 = (t & 3) * 8;

    for (int k0 = 0; k0 < K2H; k0 += 32) {
        {
            const float* pa = enc + (size_t)(b * S_ + s0 + r0) * K2H + k0 + c8;
            float4 a0 = *(const float4*)pa, a1 = *(const float4*)(pa + 4);
            float xv[8] = {a0.x, a0.y, a0.z, a0.w, a1.x, a1.y, a1.z, a1.w};
            f16x8 hh, ll;
#pragma unroll
            for (int e = 0; e < 8; e++) {
                _Float16 hi = (_Float16)xv[e];
                hh[e] = hi;
                ll[e] = (_Float16)(xv[e] - (float)hi);
            }
            *(f16x8*)&AsH[r0][c8] = hh;
            *(f16x8*)&AsL[r0][c8] = ll;
        }
        {
            const float* pb = V + (size_t)b * (L_ * K2H) + (size_t)r0 * K2H + k0 + c8;
            float4 b0 = *(const float4*)pb, b1 = *(const float4*)(pb + 4);
            float xv[8] = {b0.x, b0.y, b0.z, b0.w, b1.x, b1.y, b1.z, b1.w};
            f16x8 hh, ll;
#pragma unroll
            for (int e = 0; e < 8; e++) {
                _Float16 hi = (_Float16)xv[e];
                hh[e] = hi;
                ll[e] = (_Float16)(xv[e] - (float)hi);
            }
            *(f16x8*)&BsH[r0][c8] = hh;
            *(f16x8*)&BsL[r0][c8] = ll;
        }
        __syncthreads();
        f16x8 aH = *(const f16x8*)&AsH[w * 16 + ml][q * 8];
        f16x8 aL = *(const f16x8*)&AsL[w * 16 + ml][q * 8];
#pragma unroll
        for (int j = 0; j < 4; j++) {
            f16x8 bH = *(const f16x8*)&BsH[j * 16 + ml][q * 8];
            f16x8 bL = *(const f16x8*)&BsL[j * 16 + ml][q * 8];
            acc[j] = __builtin_amdgcn_mfma_f32_16x16x32_f16(aH, bH, acc[j], 0, 0, 0);
            acc[j] = __builtin_amdgcn_mfma_f32_16x16x32_f16(aL, bH, acc[j], 0, 0, 0);
            acc[j] = __builtin_amdgcn_mfma_f32_16x16x32_f16(aH, bL, acc[j], 0, 0, 0);
        }
        __syncthreads();
    }
#pragma unroll
    for (int j = 0; j < 4; j++) {
        const int l = j * 16 + ml;
        const float sbv = sb[b * 64 + l];
        const int srow = s0 + w * 16 + q * 4;
#pragma unroll
        for (int r = 0; r < 4; r++)
            scores[(size_t)b * (S_ * L_) + (size_t)(srow + r) * L_ + l] = acc[j][r] + sbv;
    }
}

__global__ __launch_bounds__(256) void k4_kernel(const float* __restrict__ wbuf,
                                                 const _Float16* __restrict__ reduced,
                                                 float* __restrict__ ctx) {
    __shared__ float Ws[64][64];
    __shared__ _Float16 Rs[64][256];
    const int t = threadIdx.x;
    const int b = blockIdx.x, ht = blockIdx.y, sc = blockIdx.z;
    const int h = ht * 256 + t;
    float acc[64];
#pragma unroll
    for (int l = 0; l < 64; l++) acc[l] = 0.f;

    for (int cc = 0; cc < 4; ++cc) {
        const int sbase = sc * 256 + cc * 64;
#pragma unroll
        for (int j = 0; j < 4; j++) {
            int c = t + 256 * j;
            int row = c >> 4, c4 = (c & 15) * 4;
            *(float4*)&Ws[row][c4] =
                *(const float4*)(wbuf + (size_t)b * (S_ * L_) + (size_t)(sbase + row) * L_ + c4);
        }
#pragma unroll
        for (int j = 0; j < 8; j++) {
            int c = t + 256 * j;
            int row = c >> 5, ch = (c & 31) * 8;
            *(uint4*)&Rs[row][ch] =
                *(const uint4*)(reduced + (size_t)(b * S_ + sbase + row) * H_ + ht * 256 + ch);
        }
        __syncthreads();
        for (int ss = 0; ss < 64; ++ss) {
            float r = (float)Rs[ss][t];
            const float4* wr = (const float4*)&Ws[ss][0];
#pragma unroll
            for (int u = 0; u < 16; u++) {
                float4 wv = wr[u];
                acc[u * 4 + 0] += wv.x * r;
                acc[u * 4 + 1] += wv.y * r;
                acc[u * 4 + 2] += wv.z * r;
                acc[u * 4 + 3] += wv.w * r;
            }
        }
        __syncthreads();
    }
#pragma unroll
    for (int l = 0; l < 64; l++)
        atomicAdd(ctx + (size_t)((b * 64 + l) << 10) + h, acc[l]);
}

// ================= shared (both paths) =================

__global__ __launch_bounds__(256) void k3a_kernel(const float* __restrict__ scores,
                                                  float* __restrict__ partM,
                                                  float* __restrict__ partD) {
    const int b = blockIdx.x, chunk = blockIdx.y;
    const int t = threadIdx.x;
    const int l = t & 63, si = t >> 6;
    const float* p = scores + (size_t)b * (S_ * L_) + (size_t)(chunk * 256 + si * 64) * L_ + l;
    float m = -__builtin_inff(), d = 0.f;
    for (int i = 0; i < 64; i++) {
        float x = p[i * 64];
        if (x > m) { d = d * __expf(m - x) + 1.f; m = x; }
        else d += __expf(x - m);
    }
    __shared__ float sm[256], sd[256];
    sm[t] = m; sd[t] = d; __syncthreads();
    if (t < 128) {
        float m2 = sm[t + 128], d2 = sd[t + 128];
        if (m2 > sm[t]) { sd[t] = sd[t] * __expf(sm[t] - m2) + d2; sm[t] = m2; }
        else sd[t] += d2 * __expf(m2 - sm[t]);
    }
    __syncthreads();
    if (t < 64) {
        float m1 = sm[t], d1 = sd[t], m2 = sm[t + 64], d2 = sd[t + 64];
        if (m2 > m1) { d1 = d1 * __expf(m1 - m2) + d2; m1 = m2; }
        else d1 += d2 * __expf(m2 - m1);
        partM[(b * 16 + chunk) * 64 + t] = m1;
        partD[(b * 16 + chunk) * 64 + t] = d1;
    }
}

__global__ __launch_bounds__(512) void k3b_kernel(const float* __restrict__ partM,
                                                  const float* __restrict__ partD,
                                                  float* __restrict__ fm,
                                                  float* __restrict__ fdinv) {
    const int t = threadIdx.x;
    const int b = t >> 6, l = t & 63;
    float m = -__builtin_inff(), d = 0.f;
    for (int c = 0; c < 16; c++) {
        float pm = partM[(b * 16 + c) * 64 + l];
        float pd = partD[(b * 16 + c) * 64 + l];
        if (pm > m) { d = d * __expf(m - pm) + pd; m = pm; }
        else d += pd * __expf(pm - m);
    }
    fm[t] = m;
    fdinv[t] = 1.0f / d;
}

// k3c: weights = exp(x-m)*inv_d (in place fp32) + optional fp16 A-fragment transposed copy
__global__ __launch_bounds__(256) void k3c_kernel(float* __restrict__ wbuf,
                                                  const float* __restrict__ fm,
                                                  const float* __restrict__ fdinv,
                                                  _Float16* __restrict__ watile) {
    const int base = (blockIdx.x * 256 + threadIdx.x) * 8;
    const int b = base >> 18, l0 = base & 63;
    const int s = (base >> 6) & 4095;
    float4 m0 = *(const float4*)(fm + b * 64 + l0);
    float4 m1 = *(const float4*)(fm + b * 64 + l0 + 4);
    float4 i0 = *(const float4*)(fdinv + b * 64 + l0);
    float4 i1 = *(const float4*)(fdinv + b * 64 + l0 + 4);
    float4 x0 = *(const float4*)(wbuf + base);
    float4 x1 = *(const float4*)(wbuf + base + 4);
    float y[8];
    y[0] = __expf(x0.x - m0.x) * i0.x; y[1] = __expf(x0.y - m0.y) * i0.y;
    y[2] = __expf(x0.z - m0.z) * i0.z; y[3] = __expf(x0.w - m0.w) * i0.w;
    y[4] = __expf(x1.x - m1.x) * i1.x; y[5] = __expf(x1.y - m1.y) * i1.y;
    y[6] = __expf(x1.z - m1.z) * i1.z; y[7] = __expf(x1.w - m1.w) * i1.w;
    float4 o0 = {y[0], y[1], y[2], y[3]}, o1 = {y[4], y[5], y[6], y[7]};
    *(float4*)(wbuf + base) = o0;
    *(float4*)(wbuf + base + 4) = o1;
    if (watile) {
        const size_t tbase = (((size_t)(b * 4 + (l0 >> 4)) * 128) + (s >> 5)) * 512 + (size_t)(s & 7);
        const int lane_lo = ((s >> 3) & 3) * 16;
#pragma unroll
        for (int e = 0; e < 8; e++) {
            const int l = l0 + e;
            watile[tbase + (size_t)(lane_lo + (l & 15)) * 8] = (_Float16)y[e];
        }
    }
}

extern "C" void kernel_launch(void* const* d_in, const int* in_sizes, int n_in,
                              void* d_out, int out_size, void* d_ws, size_t ws_size,
                              hipStream_t stream) {
    const float* hidden = (const float*)d_in[0];
    const float* enc    = (const float*)d_in[1];
    const float* W      = (const float*)d_in[2];
    const float* bias   = (const float*)d_in[3];

    float* ctx  = (float*)d_out;
    float* wbuf = (float*)d_out + (B_ * L_ * H_);

    char* ws = (char*)d_ws;
    const size_t NEED_FAST = 209784832;

    hipMemsetAsync(ctx, 0, (size_t)B_ * L_ * H_ * sizeof(float), stream);

    if (ws_size >= NEED_FAST) {
        _Float16* enc_hi  = (_Float16*)ws;                          // 134217728 B
        _Float16* redB    = (_Float16*)(ws + 134217728);            //  67108864 B
        _Float16* w16     = (_Float16*)(ws + 201326592);            //   4194304 B
        _Float16* vh      = (_Float16*)(ws + 205520896);            //   2097152 B
        _Float16* vl      = (_Float16*)(ws + 207618048);            //   2097152 B
        _Float16* watile  = vh;   // 4 MB alias over vh+vl (dead after kcs)
        float* partM = (float*)(ws + 209715200);
        float* partD = partM + 8 * 16 * 64;
        float* fm    = partD + 8 * 16 * 64;
        float* fdinv = fm + 512;

        kv2_kernel<<<dim3(8, 32), 256, 0, stream>>>(hidden, W, vh, vl);
        kcast_kernel<<<dim3(64, 4), 256, 0, stream>>>(W, w16, (_Float16*)nullptr);
        kcs_kernel<<<2048, 256, 0, stream>>>(enc, enc_hi, vh, vl, wbuf);
        k1f_kernel<<<2048, 256, 0, stream>>>(enc_hi, w16, bias, redB);
        k3a_kernel<<<dim3(8, 16), 256, 0, stream>>>(wbuf, partM, partD);
        k3b_kernel<<<1, 512, 0, stream>>>(partM, partD, fm, fdinv);
        k3c_kernel<<<2097152 / (256 * 8), 256, 0, stream>>>(wbuf, fm, fdinv, watile);
        k4f_kernel<<<dim3(8, 8, 8), 256, 0, stream>>>(watile, redB, ctx);
    } else {
        _Float16* reduced = (_Float16*)ws;                       // 67108864 B
        float* V     = (float*)(ws + 67108864);                  //  4194304 B
        float* partM = (float*)(ws + 71303168);
        float* partD = partM + 8 * 16 * 64;
        float* fm    = partD + 8 * 16 * 64;
        float* fdinv = fm + 512;
        float* sb    = fdinv + 512;

        ksb_kernel<<<8, 256, 0, stream>>>(hidden, bias, sb);
        kv_kernel<<<dim3(8, 32), 256, 0, stream>>>(hidden, W, V);
        k1_kernel<<<dim3(8, 256), 256, 0, stream>>>(enc, W, bias, reduced);
        ks_kernel<<<dim3(64, 8), 256, 0, stream>>>(enc, V, sb, wbuf);
        k3a_kernel<<<dim3(8, 16), 256, 0, stream>>>(wbuf, partM, partD);
        k3b_kernel<<<1, 512, 0, stream>>>(partM, partD, fm, fdinv);
        k3c_kernel<<<2097152 / (256 * 8), 256, 0, stream>>>(wbuf, fm, fdinv, (_Float16*)nullptr);
        k4_kernel<<<dim3(8, 4, 16), 256, 0, stream>>>(wbuf, reduced, ctx);
    }
}